// Round 1
// baseline (5012.087 us; speedup 1.0000x reference)
//
#include <hip/hip_runtime.h>
#include <math.h>

// Problem constants
// N=4096, F_IN=512, Z=256, H=256, E=64, ATT=128, NPER=16, B=128
static constexpr int BKc = 16;

__device__ __forceinline__ float wave_reduce_sum(float v) {
#pragma unroll
  for (int off = 32; off > 0; off >>= 1) v += __shfl_down(v, off);
  return v;
}

// ---------------------------------------------------------------------------
// Pass over the 4 input adjacencies: row sums, diagonals, and tmp matrix
// tmp = 0.5*w0*(c0+c1) + 0.5*w1*(d0+d1)   (w from wb_z1)
// ---------------------------------------------------------------------------
__global__ __launch_bounds__(256) void k_rowsums(
    const float* __restrict__ c0, const float* __restrict__ c1,
    const float* __restrict__ d0, const float* __restrict__ d1,
    const float* __restrict__ wb, float* __restrict__ tmp,
    float* __restrict__ rs_c0, float* __restrict__ rs_c1,
    float* __restrict__ rs_d0, float* __restrict__ rs_d1,
    float* __restrict__ dg_c0, float* __restrict__ dg_c1,
    float* __restrict__ dg_d0, float* __restrict__ dg_d1) {
  int wave = threadIdx.x >> 6, lane = threadIdx.x & 63;
  float hw0 = 0.5f * wb[0], hw1 = 0.5f * wb[1];
  int rbase = blockIdx.x * 16 + wave * 4;
  for (int i = 0; i < 4; ++i) {
    int row = rbase + i;
    const float* pc0 = c0 + (size_t)row * 4096;
    const float* pc1 = c1 + (size_t)row * 4096;
    const float* pd0 = d0 + (size_t)row * 4096;
    const float* pd1 = d1 + (size_t)row * 4096;
    float* pt = tmp + (size_t)row * 4096;
    float s0 = 0.f, s1 = 0.f, s2 = 0.f, s3 = 0.f;
    for (int ct = 0; ct < 64; ++ct) {
      int col = ct * 64 + lane;
      float a = pc0[col], b = pc1[col], e = pd0[col], f = pd1[col];
      s0 += a; s1 += b; s2 += e; s3 += f;
      pt[col] = hw0 * (a + b) + hw1 * (e + f);
      if (col == row) { dg_c0[row] = a; dg_c1[row] = b; dg_d0[row] = e; dg_d1[row] = f; }
    }
    s0 = wave_reduce_sum(s0); s1 = wave_reduce_sum(s1);
    s2 = wave_reduce_sum(s2); s3 = wave_reduce_sum(s3);
    if (lane == 0) { rs_c0[row] = s0; rs_c1[row] = s1; rs_d0[row] = s2; rs_d1[row] = s3; }
  }
}

// Column sums of a 4096x4096 matrix, atomically accumulated (cs must be pre-zeroed)
__global__ __launch_bounds__(256) void k_colsum(const float* __restrict__ T,
                                                float* __restrict__ cs) {
  int c = blockIdx.x * 256 + threadIdx.x;
  int r0 = blockIdx.y * 128;
  float a = 0.f;
  for (int r = r0; r < r0 + 128; ++r) a += T[(size_t)r * 4096 + c];
  atomicAdd(&cs[c], a);
}

// A1 = tmp + tmp^T
__global__ __launch_bounds__(256) void k_addT(const float* __restrict__ T,
                                              float* __restrict__ A1) {
  __shared__ float t[64][65];
  int bi = blockIdx.y, bj = blockIdx.x;
  int lane = threadIdx.x & 63, w = threadIdx.x >> 6;
  for (int i = w; i < 64; i += 4)
    t[i][lane] = T[(size_t)(bj * 64 + i) * 4096 + bi * 64 + lane];
  __syncthreads();
  for (int i = w; i < 64; i += 4) {
    size_t idx = (size_t)(bi * 64 + i) * 4096 + bj * 64 + lane;
    A1[idx] = T[idx] + t[lane][i];
  }
}

// Finalize degree vectors and raw-diagonal vectors for the propagation epilogues
__global__ __launch_bounds__(256) void k_fin(
    const float* __restrict__ rs_c0, const float* __restrict__ rs_c1,
    const float* __restrict__ rs_d0, const float* __restrict__ rs_d1,
    const float* __restrict__ dg_c0, const float* __restrict__ dg_c1,
    const float* __restrict__ dg_d0, const float* __restrict__ dg_d1,
    const float* __restrict__ cs_tmp, const float* __restrict__ wb,
    float* __restrict__ d_c0, float* __restrict__ d_c1,
    float* __restrict__ d_dd0, float* __restrict__ d_dd1, float* __restrict__ d_A1,
    float* __restrict__ gP_dd0, float* __restrict__ gP_dd1, float* __restrict__ gP_A1) {
  int n = blockIdx.x * 256 + threadIdx.x;
  float rc0 = rs_c0[n], rc1 = rs_c1[n], rd0 = rs_d0[n], rd1 = rs_d1[n];
  float gc0 = dg_c0[n], gc1 = dg_c1[n], gd0 = dg_d0[n], gd1 = dg_d1[n];
  d_c0[n] = rsqrtf(fmaxf(rc0 - gc0 + 1.f, 1.f));
  d_c1[n] = rsqrtf(fmaxf(rc1 - gc1 + 1.f, 1.f));
  float cmr = 0.5f * (rc0 + rc1), cmg = 0.5f * (gc0 + gc1);
  float g0 = gd0 + cmg; gP_dd0[n] = g0;
  d_dd0[n] = rsqrtf(fmaxf(rd0 + cmr - g0 + 1.f, 1.f));
  float g1 = gd1 + cmg; gP_dd1[n] = g1;
  d_dd1[n] = rsqrtf(fmaxf(rd1 + cmr - g1 + 1.f, 1.f));
  float w0 = wb[0], w1 = wb[1];
  float rt = w0 * cmr + w1 * 0.5f * (rd0 + rd1);
  float gt = w0 * cmg + w1 * 0.5f * (gd0 + gd1);
  gP_A1[n] = 2.f * gt;
  d_A1[n] = rsqrtf(fmaxf(rt + cs_tmp[n] - 2.f * gt + 1.f, 1.f));
}

// Finalize A2 degree vector
__global__ __launch_bounds__(256) void k_dA2(const float* __restrict__ A2,
                                             const float* __restrict__ rs,
                                             float* __restrict__ dvec,
                                             float* __restrict__ gP) {
  int n = blockIdx.x * 256 + threadIdx.x;
  float dg = A2[(size_t)n * 4096 + n];
  gP[n] = dg;
  dvec[n] = rsqrtf(fmaxf(rs[n] - dg + 1.f, 1.f));
}

// ---------------------------------------------------------------------------
// Generic fp32 GEMM.  C[M,Nc] = epilogue(A[M,K] @ B)
//  BT=0: B is [K,Nc] row-major.  BT=1: B is [Nc,K] row-major (C = A@B^T).
//  AMODE: 0 plain A; 1: A_eff = A + 0.5*(Ax0+Ax1)    (diff-GCN adjacency)
//  EPI: 0 none; 1 relu(acc+bias); 2 sigmoid(relu(acc+bias));
//       3 A2-combine: C = 0.125*(w0*relu(aux)+w1*relu(acc));
//       4 GCN prop: B-rows scaled by dvec[k]; C = relu(d[n]*(acc+(1-diag[n])*d[n]*xw[n,c])+bias[c])
// ---------------------------------------------------------------------------
template <int BM, int BN, int RT, int CT, int AMODE, int EPI, int BT>
__global__ __launch_bounds__(256) void gemm_k(
    const float* __restrict__ A, const float* __restrict__ Ax0,
    const float* __restrict__ Ax1, const float* __restrict__ B,
    float* __restrict__ C, int M, int Nc, int K, int lda, int ldb, int ldc,
    const float* __restrict__ bias, const float* __restrict__ dvec,
    const float* __restrict__ diagA, const float* __restrict__ xw, int ldxw,
    const float* __restrict__ aux, const float* __restrict__ wb) {
  __shared__ float As[BKc][BM + 4];
  __shared__ float Bs[BKc][BN];
  const int tid = threadIdx.x;
  const int m0 = blockIdx.y * BM, n0 = blockIdx.x * BN;
  constexpr int COLG = BN / CT;  // 16
  const int ty = tid / COLG, tx = tid % COLG;
  float acc[RT][CT] = {};

  for (int k0 = 0; k0 < K; k0 += BKc) {
    // ---- A tile (store k-major) ----
    if constexpr (BM == 64) {
      int r = tid >> 2, kc = (tid & 3) * 4;
      size_t base = (size_t)(m0 + r) * lda + k0 + kc;
      float4 v = *(const float4*)(A + base);
      if constexpr (AMODE == 1) {
        float4 u = *(const float4*)(Ax0 + base);
        float4 w = *(const float4*)(Ax1 + base);
        v.x += 0.5f * (u.x + w.x); v.y += 0.5f * (u.y + w.y);
        v.z += 0.5f * (u.z + w.z); v.w += 0.5f * (u.w + w.w);
      }
      As[kc + 0][r] = v.x; As[kc + 1][r] = v.y; As[kc + 2][r] = v.z; As[kc + 3][r] = v.w;
    } else {  // BM == 32
      int r = tid >> 3, kc = (tid & 7) * 2;
      size_t base = (size_t)(m0 + r) * lda + k0 + kc;
      float2 v = *(const float2*)(A + base);
      if constexpr (AMODE == 1) {
        float2 u = *(const float2*)(Ax0 + base);
        float2 w = *(const float2*)(Ax1 + base);
        v.x += 0.5f * (u.x + w.x); v.y += 0.5f * (u.y + w.y);
      }
      As[kc + 0][r] = v.x; As[kc + 1][r] = v.y;
    }
    // ---- B tile ----
    if constexpr (BT == 0) {
      constexpr int C4 = BN / 4;
#pragma unroll
      for (int it = 0; it < (BN * BKc) / (256 * 4); ++it) {
        int idx = tid + it * 256;
        int kk = idx / C4;
        int c4 = (idx % C4) * 4;
        int col = n0 + c4;
        float4 v = make_float4(0.f, 0.f, 0.f, 0.f);
        if (col < Nc) v = *(const float4*)(B + (size_t)(k0 + kk) * ldb + col);
        if constexpr (EPI == 4) {
          float d = dvec[k0 + kk];
          v.x *= d; v.y *= d; v.z *= d; v.w *= d;
        }
        *(float4*)&Bs[kk][c4] = v;
      }
    } else {
#pragma unroll
      for (int it = 0; it < (BN * BKc) / (256 * 4); ++it) {
        int idx = tid + it * 256;
        int nn = idx >> 2, kc = (idx & 3) * 4;
        float4 v = *(const float4*)(B + (size_t)(n0 + nn) * ldb + k0 + kc);
        Bs[kc + 0][nn] = v.x; Bs[kc + 1][nn] = v.y; Bs[kc + 2][nn] = v.z; Bs[kc + 3][nn] = v.w;
      }
    }
    __syncthreads();
#pragma unroll
    for (int kk = 0; kk < BKc; ++kk) {
      float a[RT];
      if constexpr (RT == 4) {
        float4 av = *(const float4*)&As[kk][ty * 4];
        a[0] = av.x; a[1] = av.y; a[2] = av.z; a[3] = av.w;
      } else {
        float2 av = *(const float2*)&As[kk][ty * 2];
        a[0] = av.x; a[1] = av.y;
      }
      float4 b0 = *(const float4*)&Bs[kk][tx * CT];
      float4 b1 = *(const float4*)&Bs[kk][tx * CT + 4];
      float b[8] = {b0.x, b0.y, b0.z, b0.w, b1.x, b1.y, b1.z, b1.w};
#pragma unroll
      for (int i = 0; i < RT; ++i)
#pragma unroll
        for (int j = 0; j < CT; ++j) acc[i][j] += a[i] * b[j];
    }
    __syncthreads();
  }
  // ---- epilogue ----
  float w0 = 0.f, w1 = 0.f;
  if constexpr (EPI == 3) { w0 = wb[0]; w1 = wb[1]; }
#pragma unroll
  for (int i = 0; i < RT; ++i) {
    int row = m0 + ty * RT + i;
    float dn = 0.f, dfix = 0.f;
    if constexpr (EPI == 4) {
      dn = dvec[row];
      dfix = (1.f - diagA[row]) * dn;
    }
#pragma unroll
    for (int j = 0; j < CT; ++j) {
      int col = n0 + tx * CT + j;
      if (col >= Nc) continue;
      float v = acc[i][j];
      size_t oi = (size_t)row * ldc + col;
      if constexpr (EPI == 0) {
        C[oi] = v;
      } else if constexpr (EPI == 1) {
        C[oi] = fmaxf(v + bias[col], 0.f);
      } else if constexpr (EPI == 2) {
        float r_ = fmaxf(v + bias[col], 0.f);
        C[oi] = 1.f / (1.f + expf(-r_));
      } else if constexpr (EPI == 3) {
        C[oi] = 0.125f * (w0 * fmaxf(aux[oi], 0.f) + w1 * fmaxf(v, 0.f));
      } else if constexpr (EPI == 4) {
        float xwv = xw[(size_t)row * ldxw + col];
        C[oi] = fmaxf(dn * (v + dfix * xwv) + bias[col], 0.f);
      }
    }
  }
}

// ---------------------------------------------------------------------------
// Attention score accumulation: s[k] += sum_n tanh(z_k[n,:]@W1 + b1)@w2
// ---------------------------------------------------------------------------
__global__ __launch_bounds__(256) void k_att(
    const float* __restrict__ z0, const float* __restrict__ z1,
    const float* __restrict__ z2, const float* __restrict__ z3,
    const float* __restrict__ W1, const float* __restrict__ b1,
    const float* __restrict__ w2, float* __restrict__ s_out) {
  int k = blockIdx.y;
  const float* z = (k == 0) ? z0 : (k == 1) ? z1 : (k == 2) ? z2 : z3;
  int wave = threadIdx.x >> 6, lane = threadIdx.x & 63;
  float total = 0.f;
  for (int n = blockIdx.x * 4 + wave; n < 4096; n += gridDim.x * 4) {
    float s0 = 0.f, s1 = 0.f;
    const float* zr = z + (size_t)n * 256;
    for (int h = 0; h < 256; ++h) {
      float zv = zr[h];
      s0 += zv * W1[h * 128 + lane];
      s1 += zv * W1[h * 128 + 64 + lane];
    }
    float v = tanhf(s0 + b1[lane]) * w2[lane] + tanhf(s1 + b1[64 + lane]) * w2[64 + lane];
    v = wave_reduce_sum(v);
    if (lane == 0) total += v;
  }
  if (lane == 0) atomicAdd(&s_out[k], total);
}

__global__ void k_beta(const float* __restrict__ s, float* __restrict__ bb) {
  if (threadIdx.x == 0 && blockIdx.x == 0) {
    const float inv = 1.f / 4096.f;
    float c0 = s[0] * inv, c1 = s[1] * inv;
    float m = fmaxf(c0, c1);
    float e0 = expf(c0 - m), e1 = expf(c1 - m);
    float is = 1.f / (e0 + e1);
    bb[0] = e0 * is; bb[1] = e1 * is;
    float d0 = s[2] * inv, d1 = s[3] * inv, d2 = s[4] * inv, d3 = s[5] * inv;
    float md = fmaxf(fmaxf(d0, d1), fmaxf(d2, d3));
    float f0 = expf(d0 - md), f1 = expf(d1 - md), f2 = expf(d2 - md), f3 = expf(d3 - md);
    float id = 1.f / (f0 + f1 + f2 + f3);
    bb[2] = f0 * id; bb[3] = f1 * id; bb[4] = f2 * id; bb[5] = f3 * id;
  }
}

__global__ __launch_bounds__(256) void k_agg(
    const float* __restrict__ cr0, const float* __restrict__ cr1,
    const float* __restrict__ dr0, const float* __restrict__ dr1,
    const float* __restrict__ bb, float* __restrict__ cagg, float* __restrict__ dagg) {
  size_t i = ((size_t)blockIdx.x * 256 + threadIdx.x) * 4;
  float4 a = *(const float4*)(cr0 + i);
  float4 b = *(const float4*)(cr1 + i);
  float4 c = *(const float4*)(dr0 + i);
  float4 d = *(const float4*)(dr1 + i);
  float bc0 = bb[0], bc1 = bb[1], bd0 = bb[2], bd1 = bb[3], bd2 = bb[4], bd3 = bb[5];
  float4 ca, da;
  ca.x = bc0 * a.x + bc1 * b.x; ca.y = bc0 * a.y + bc1 * b.y;
  ca.z = bc0 * a.z + bc1 * b.z; ca.w = bc0 * a.w + bc1 * b.w;
  da.x = bd0 * a.x + bd1 * b.x + bd2 * c.x + bd3 * d.x;
  da.y = bd0 * a.y + bd1 * b.y + bd2 * c.y + bd3 * d.y;
  da.z = bd0 * a.z + bd1 * b.z + bd2 * c.z + bd3 * d.z;
  da.w = bd0 * a.w + bd1 * b.w + bd2 * c.w + bd3 * d.w;
  *(float4*)(cagg + i) = ca;
  *(float4*)(dagg + i) = da;
}

// cn[n, p*64+e] = (mu[n,e]*Wt[p,e]) / max(||mu[n,:]*Wt[p,:]||, 1e-12)
__global__ __launch_bounds__(256) void k_cn(const float* __restrict__ mu,
                                            const float* __restrict__ Wt,
                                            float* __restrict__ Cn) {
  int g = blockIdx.x * 4 + (threadIdx.x >> 6);
  int lane = threadIdx.x & 63;
  int n = g >> 4, p = g & 15;
  float v = mu[(size_t)n * 64 + lane] * Wt[p * 64 + lane];
  float ss = v * v;
#pragma unroll
  for (int off = 32; off > 0; off >>= 1) ss += __shfl_xor(ss, off);
  float nrm = fmaxf(sqrtf(ss), 1e-12f);
  Cn[(size_t)n * 1024 + p * 64 + lane] = v / nrm;
}

__global__ __launch_bounds__(256) void k_gather(
    const int* __restrict__ xs, const float* __restrict__ U1, const float* __restrict__ U2,
    const float* __restrict__ V1, const float* __restrict__ V2, float* __restrict__ out) {
  int b = blockIdx.x, j = threadIdx.x;
  int row = xs[b];
  size_t r = (size_t)row * 256;
  out[(size_t)b * 512 + j] = 0.5f * (U1[r + j] + U2[r + j]);
  out[(size_t)b * 512 + 256 + j] = 0.5f * (V1[r + j] + V2[r + j]);
}

// ---------------------------------------------------------------------------
extern "C" void kernel_launch(void* const* d_in, const int* in_sizes, int n_in,
                              void* d_out, int out_size, void* d_ws, size_t ws_size,
                              hipStream_t stream) {
  const float* c0adj = (const float*)d_in[0];
  const float* c1adj = (const float*)d_in[1];
  const float* d0adj = (const float*)d_in[2];
  const float* d1adj = (const float*)d_in[3];
  const float* feats = (const float*)d_in[4];
  const float* W_comm = (const float*)d_in[5];
  const float* b_comm = (const float*)d_in[6];
  const float* W_diff = (const float*)d_in[7];
  const float* b_diff = (const float*)d_in[8];
  const float* W_catt1 = (const float*)d_in[9];
  const float* b_catt1 = (const float*)d_in[10];
  const float* w_catt2 = (const float*)d_in[11];
  const float* W_datt1 = (const float*)d_in[12];
  const float* b_datt1 = (const float*)d_in[13];
  const float* w_datt2 = (const float*)d_in[14];
  const float* W_mu_c = (const float*)d_in[15];
  const float* b_mu_c = (const float*)d_in[16];
  const float* W_var_c = (const float*)d_in[17];
  const float* b_var_c = (const float*)d_in[18];
  const float* W_mu_d = (const float*)d_in[19];
  const float* b_mu_d = (const float*)d_in[20];
  const float* W_var_d = (const float*)d_in[21];
  const float* b_var_d = (const float*)d_in[22];
  const float* W_z1_1 = (const float*)d_in[23];
  const float* b_z1_1 = (const float*)d_in[24];
  const float* W_z1_2 = (const float*)d_in[25];
  const float* b_z1_2 = (const float*)d_in[26];
  const float* wb_z1 = (const float*)d_in[27];
  const float* Wt_c = (const float*)d_in[28];
  const float* Wt_d = (const float*)d_in[29];
  const float* W_z2_1 = (const float*)d_in[30];
  const float* b_z2_1 = (const float*)d_in[31];
  const float* W_z2_2 = (const float*)d_in[32];
  const float* b_z2_2 = (const float*)d_in[33];
  const float* wb_z2 = (const float*)d_in[34];
  const int* xs = (const int*)d_in[35];

  float* out = (float*)d_out;
  float* out_muc = out + 65536;
  float* out_varc = out + 327680;
  float* out_mud = out + 589824;
  float* out_vard = out + 851968;

  float* ws = (float*)d_ws;
  const size_t M1 = 1048576;  // 4096*256
  float* xw_comm = ws + 0 * M1;
  float* xw_diff = ws + 1 * M1;
  float* xw_z1 = ws + 2 * M1;
  float* xw_z2 = ws + 3 * M1;
  float* cr0 = ws + 4 * M1;
  float* cr1 = ws + 5 * M1;
  float* dr0 = ws + 6 * M1;
  float* dr1 = ws + 7 * M1;
  float* u1 = ws + 8 * M1;
  float* u2 = ws + 9 * M1;
  float* v1 = ws + 10 * M1;
  float* v2 = ws + 11 * M1;
  float* uw = ws + 12 * M1;
  float* cagg = ws + 13 * M1;
  float* dagg = ws + 14 * M1;
  float* Cc = ws + 15 * M1;    // 4*M1 floats
  float* Cd = ws + 19 * M1;    // 4*M1 floats
  float* tmpb = ws + 23 * M1;  // 16*M1 floats (reused as T1)
  float* a1b = ws + 39 * M1;   // 16*M1 floats (A1, later reused as A2)
  float* vecs = ws + 55 * M1;
#define VV(i) (vecs + (size_t)(i) * 4096)
  float* rs_c0 = VV(0); float* rs_c1 = VV(1); float* rs_d0 = VV(2); float* rs_d1 = VV(3);
  float* dg_c0 = VV(4); float* dg_c1 = VV(5); float* dg_d0 = VV(6); float* dg_d1 = VV(7);
  float* cs_tmp = VV(8); float* rs_A2 = VV(9);
  float* d_c0 = VV(10); float* d_c1 = VV(11); float* d_dd0 = VV(12); float* d_dd1 = VV(13);
  float* d_A1 = VV(14); float* d_A2 = VV(15);
  float* gP_dd0 = VV(16); float* gP_dd1 = VV(17); float* gP_A1 = VV(18); float* gP_A2 = VV(19);
  float* satt = VV(20);
  float* beta = satt + 8;

  // zero atomic accumulators (cs_tmp, rs_A2 contiguous; satt region)
  hipMemsetAsync(cs_tmp, 0, 2 * 4096 * sizeof(float), stream);
  hipMemsetAsync(satt, 0, 32, stream);

  // adjacency pass: rowsums + diags + tmp
  k_rowsums<<<256, 256, 0, stream>>>(c0adj, c1adj, d0adj, d1adj, wb_z1, tmpb,
                                     rs_c0, rs_c1, rs_d0, rs_d1, dg_c0, dg_c1, dg_d0, dg_d1);
  k_colsum<<<dim3(16, 32), 256, 0, stream>>>(tmpb, cs_tmp);
  k_fin<<<16, 256, 0, stream>>>(rs_c0, rs_c1, rs_d0, rs_d1, dg_c0, dg_c1, dg_d0, dg_d1,
                                cs_tmp, wb_z1, d_c0, d_c1, d_dd0, d_dd1, d_A1,
                                gP_dd0, gP_dd1, gP_A1);
  k_addT<<<dim3(64, 64), 256, 0, stream>>>(tmpb, a1b);

  // feats @ W  (4x)
  gemm_k<32, 128, 2, 8, 0, 0, 0><<<dim3(2, 128), 256, 0, stream>>>(
      feats, nullptr, nullptr, W_comm, xw_comm, 4096, 256, 512, 512, 256, 256,
      nullptr, nullptr, nullptr, nullptr, 0, nullptr, nullptr);
  gemm_k<32, 128, 2, 8, 0, 0, 0><<<dim3(2, 128), 256, 0, stream>>>(
      feats, nullptr, nullptr, W_diff, xw_diff, 4096, 256, 512, 512, 256, 256,
      nullptr, nullptr, nullptr, nullptr, 0, nullptr, nullptr);
  gemm_k<32, 128, 2, 8, 0, 0, 0><<<dim3(2, 128), 256, 0, stream>>>(
      feats, nullptr, nullptr, W_z1_1, xw_z1, 4096, 256, 512, 512, 256, 256,
      nullptr, nullptr, nullptr, nullptr, 0, nullptr, nullptr);
  gemm_k<32, 128, 2, 8, 0, 0, 0><<<dim3(2, 128), 256, 0, stream>>>(
      feats, nullptr, nullptr, W_z2_1, xw_z2, 4096, 256, 512, 512, 256, 256,
      nullptr, nullptr, nullptr, nullptr, 0, nullptr, nullptr);

  // GCN propagations: comm reps
  gemm_k<32, 128, 2, 8, 0, 4, 0><<<dim3(2, 128), 256, 0, stream>>>(
      c0adj, nullptr, nullptr, xw_comm, cr0, 4096, 256, 4096, 4096, 256, 256,
      b_comm, d_c0, dg_c0, xw_comm, 256, nullptr, nullptr);
  gemm_k<32, 128, 2, 8, 0, 4, 0><<<dim3(2, 128), 256, 0, stream>>>(
      c1adj, nullptr, nullptr, xw_comm, cr1, 4096, 256, 4096, 4096, 256, 256,
      b_comm, d_c1, dg_c1, xw_comm, 256, nullptr, nullptr);
  // diff reps (adjacency = diff_i + 0.5*(c0+c1), formed on the fly)
  gemm_k<32, 128, 2, 8, 1, 4, 0><<<dim3(2, 128), 256, 0, stream>>>(
      d0adj, c0adj, c1adj, xw_diff, dr0, 4096, 256, 4096, 4096, 256, 256,
      b_diff, d_dd0, gP_dd0, xw_diff, 256, nullptr, nullptr);
  gemm_k<32, 128, 2, 8, 1, 4, 0><<<dim3(2, 128), 256, 0, stream>>>(
      d1adj, c0adj, c1adj, xw_diff, dr1, 4096, 256, 4096, 4096, 256, 256,
      b_diff, d_dd1, gP_dd1, xw_diff, 256, nullptr, nullptr);
  // z1 branch: U1 then U2
  gemm_k<32, 128, 2, 8, 0, 4, 0><<<dim3(2, 128), 256, 0, stream>>>(
      a1b, nullptr, nullptr, xw_z1, u1, 4096, 256, 4096, 4096, 256, 256,
      b_z1_1, d_A1, gP_A1, xw_z1, 256, nullptr, nullptr);
  gemm_k<32, 128, 2, 8, 0, 0, 0><<<dim3(2, 128), 256, 0, stream>>>(
      u1, nullptr, nullptr, W_z1_2, uw, 4096, 256, 256, 256, 256, 256,
      nullptr, nullptr, nullptr, nullptr, 0, nullptr, nullptr);
  gemm_k<32, 128, 2, 8, 0, 4, 0><<<dim3(2, 128), 256, 0, stream>>>(
      a1b, nullptr, nullptr, uw, u2, 4096, 256, 4096, 4096, 256, 256,
      b_z1_2, d_A1, gP_A1, uw, 256, nullptr, nullptr);

  // attention
  k_att<<<dim3(64, 2), 256, 0, stream>>>(cr0, cr1, cr0, cr0, W_catt1, b_catt1, w_catt2, satt);
  k_att<<<dim3(64, 4), 256, 0, stream>>>(cr0, cr1, dr0, dr1, W_datt1, b_datt1, w_datt2, satt + 2);
  k_beta<<<1, 64, 0, stream>>>(satt, beta);
  k_agg<<<1024, 256, 0, stream>>>(cr0, cr1, dr0, dr1, beta, cagg, dagg);

  // heads -> outputs (mu_c/var_c/mu_d/var_d)
  gemm_k<32, 128, 2, 8, 0, 1, 0><<<dim3(1, 128), 256, 0, stream>>>(
      cagg, nullptr, nullptr, W_mu_c, out_muc, 4096, 64, 256, 256, 64, 64,
      b_mu_c, nullptr, nullptr, nullptr, 0, nullptr, nullptr);
  gemm_k<32, 128, 2, 8, 0, 2, 0><<<dim3(1, 128), 256, 0, stream>>>(
      cagg, nullptr, nullptr, W_var_c, out_varc, 4096, 64, 256, 256, 64, 64,
      b_var_c, nullptr, nullptr, nullptr, 0, nullptr, nullptr);
  gemm_k<32, 128, 2, 8, 0, 1, 0><<<dim3(1, 128), 256, 0, stream>>>(
      dagg, nullptr, nullptr, W_mu_d, out_mud, 4096, 64, 256, 256, 64, 64,
      b_mu_d, nullptr, nullptr, nullptr, 0, nullptr, nullptr);
  gemm_k<32, 128, 2, 8, 0, 2, 0><<<dim3(1, 128), 256, 0, stream>>>(
      dagg, nullptr, nullptr, W_var_d, out_vard, 4096, 64, 256, 256, 64, 64,
      b_var_d, nullptr, nullptr, nullptr, 0, nullptr, nullptr);

  // cosine contexts
  k_cn<<<16384, 256, 0, stream>>>(out_muc, Wt_c, Cc);
  k_cn<<<16384, 256, 0, stream>>>(out_mud, Wt_d, Cd);

  // T1 = Cc@Cc^T (raw), then A2 = 0.125*(w0*relu(T1)+w1*relu(Cd@Cd^T))
  gemm_k<64, 128, 4, 8, 0, 0, 1><<<dim3(32, 64), 256, 0, stream>>>(
      Cc, nullptr, nullptr, Cc, tmpb, 4096, 4096, 1024, 1024, 1024, 4096,
      nullptr, nullptr, nullptr, nullptr, 0, nullptr, nullptr);
  gemm_k<64, 128, 4, 8, 0, 3, 1><<<dim3(32, 64), 256, 0, stream>>>(
      Cd, nullptr, nullptr, Cd, a1b, 4096, 4096, 1024, 1024, 1024, 4096,
      nullptr, nullptr, nullptr, nullptr, 0, tmpb, wb_z2);

  // A2 degrees (A2 symmetric: colsum == rowsum)
  k_colsum<<<dim3(16, 32), 256, 0, stream>>>(a1b, rs_A2);
  k_dA2<<<16, 256, 0, stream>>>(a1b, rs_A2, d_A2, gP_A2);

  // z2 branch: V1 then V2
  gemm_k<32, 128, 2, 8, 0, 4, 0><<<dim3(2, 128), 256, 0, stream>>>(
      a1b, nullptr, nullptr, xw_z2, v1, 4096, 256, 4096, 4096, 256, 256,
      b_z2_1, d_A2, gP_A2, xw_z2, 256, nullptr, nullptr);
  gemm_k<32, 128, 2, 8, 0, 0, 0><<<dim3(2, 128), 256, 0, stream>>>(
      v1, nullptr, nullptr, W_z2_2, uw, 4096, 256, 256, 256, 256, 256,
      nullptr, nullptr, nullptr, nullptr, 0, nullptr, nullptr);
  gemm_k<32, 128, 2, 8, 0, 4, 0><<<dim3(2, 128), 256, 0, stream>>>(
      a1b, nullptr, nullptr, uw, v2, 4096, 256, 4096, 4096, 256, 256,
      b_z2_2, d_A2, gP_A2, uw, 256, nullptr, nullptr);

  // h[xs]
  k_gather<<<128, 256, 0, stream>>>(xs, u1, u2, v1, v2, out);
}

// Round 2
// 2531.744 us; speedup vs baseline: 1.9797x; 1.9797x over previous
//
#include <hip/hip_runtime.h>
#include <math.h>

// N=4096, F_IN=512, Z=256, H=256, E=64, ATT=128, NPER=16, B=128
using f32x4 = __attribute__((ext_vector_type(4))) float;
using bf16x8 = __attribute__((ext_vector_type(8))) short;

__device__ __forceinline__ float wave_reduce_sum(float v) {
#pragma unroll
  for (int off = 32; off > 0; off >>= 1) v += __shfl_down(v, off);
  return v;
}

__device__ __forceinline__ unsigned short f2bf_rne(float x) {
  unsigned int u = __float_as_uint(x);
  unsigned int r = u + 0x7FFFu + ((u >> 16) & 1u);
  return (unsigned short)(r >> 16);
}
// split x = hi + lo, hi = truncated-bf16(x) (exact residual), lo = rne-bf16(residual)
__device__ __forceinline__ void split1(float x, unsigned short& h, unsigned short& l) {
  unsigned int u = __float_as_uint(x);
  h = (unsigned short)(u >> 16);
  float rem = x - __uint_as_float(u & 0xFFFF0000u);
  l = f2bf_rne(rem);
}
__device__ __forceinline__ void split8(const float* f, bf16x8& h, bf16x8& l) {
#pragma unroll
  for (int i = 0; i < 8; ++i) {
    unsigned short hh, ll;
    split1(f[i], hh, ll);
    h[i] = (short)hh;
    l[i] = (short)ll;
  }
}

// ---------------------------------------------------------------------------
// Adjacency pass: row sums, diagonals, tmp = 0.5*w0*(c0+c1) + 0.5*w1*(d0+d1)
// ---------------------------------------------------------------------------
__global__ __launch_bounds__(256) void k_rowsums(
    const float* __restrict__ c0, const float* __restrict__ c1,
    const float* __restrict__ d0, const float* __restrict__ d1,
    const float* __restrict__ wb, float* __restrict__ tmp,
    float* __restrict__ rs_c0, float* __restrict__ rs_c1,
    float* __restrict__ rs_d0, float* __restrict__ rs_d1,
    float* __restrict__ dg_c0, float* __restrict__ dg_c1,
    float* __restrict__ dg_d0, float* __restrict__ dg_d1) {
  int wave = threadIdx.x >> 6, lane = threadIdx.x & 63;
  float hw0 = 0.5f * wb[0], hw1 = 0.5f * wb[1];
  int rbase = blockIdx.x * 16 + wave * 4;
  for (int i = 0; i < 4; ++i) {
    int row = rbase + i;
    const float* pc0 = c0 + (size_t)row * 4096;
    const float* pc1 = c1 + (size_t)row * 4096;
    const float* pd0 = d0 + (size_t)row * 4096;
    const float* pd1 = d1 + (size_t)row * 4096;
    float* pt = tmp + (size_t)row * 4096;
    float s0 = 0.f, s1 = 0.f, s2 = 0.f, s3 = 0.f;
    for (int ct = 0; ct < 64; ++ct) {
      int col = ct * 64 + lane;
      float a = pc0[col], b = pc1[col], e = pd0[col], f = pd1[col];
      s0 += a; s1 += b; s2 += e; s3 += f;
      pt[col] = hw0 * (a + b) + hw1 * (e + f);
      if (col == row) { dg_c0[row] = a; dg_c1[row] = b; dg_d0[row] = e; dg_d1[row] = f; }
    }
    s0 = wave_reduce_sum(s0); s1 = wave_reduce_sum(s1);
    s2 = wave_reduce_sum(s2); s3 = wave_reduce_sum(s3);
    if (lane == 0) { rs_c0[row] = s0; rs_c1[row] = s1; rs_d0[row] = s2; rs_d1[row] = s3; }
  }
}

// Column sums of a 4096x4096 fp32 matrix (cs pre-zeroed)
__global__ __launch_bounds__(256) void k_colsum(const float* __restrict__ T,
                                                float* __restrict__ cs) {
  int c = blockIdx.x * 256 + threadIdx.x;
  int r0 = blockIdx.y * 128;
  float a = 0.f;
  for (int r = r0; r < r0 + 128; ++r) a += T[(size_t)r * 4096 + c];
  atomicAdd(&cs[c], a);
}

// A1 = tmp + tmp^T, written as split-bf16 pair
__global__ __launch_bounds__(256) void k_addT(const float* __restrict__ T,
                                              unsigned short* __restrict__ A1h,
                                              unsigned short* __restrict__ A1l) {
  __shared__ float t[64][65];
  int bi = blockIdx.y, bj = blockIdx.x;
  int lane = threadIdx.x & 63, w = threadIdx.x >> 6;
  for (int i = w; i < 64; i += 4)
    t[i][lane] = T[(size_t)(bj * 64 + i) * 4096 + bi * 64 + lane];
  __syncthreads();
  for (int i = w; i < 64; i += 4) {
    size_t idx = (size_t)(bi * 64 + i) * 4096 + bj * 64 + lane;
    float v = T[idx] + t[lane][i];
    unsigned short h, l;
    split1(v, h, l);
    A1h[idx] = h; A1l[idx] = l;
  }
}

// degree/diag finalization for c0,c1,diff0,diff1,A1
__global__ __launch_bounds__(256) void k_fin(
    const float* __restrict__ rs_c0, const float* __restrict__ rs_c1,
    const float* __restrict__ rs_d0, const float* __restrict__ rs_d1,
    const float* __restrict__ dg_c0, const float* __restrict__ dg_c1,
    const float* __restrict__ dg_d0, const float* __restrict__ dg_d1,
    const float* __restrict__ cs_tmp, const float* __restrict__ wb,
    float* __restrict__ d_c0, float* __restrict__ d_c1,
    float* __restrict__ d_dd0, float* __restrict__ d_dd1, float* __restrict__ d_A1,
    float* __restrict__ gP_dd0, float* __restrict__ gP_dd1, float* __restrict__ gP_A1) {
  int n = blockIdx.x * 256 + threadIdx.x;
  float rc0 = rs_c0[n], rc1 = rs_c1[n], rd0 = rs_d0[n], rd1 = rs_d1[n];
  float gc0 = dg_c0[n], gc1 = dg_c1[n], gd0 = dg_d0[n], gd1 = dg_d1[n];
  d_c0[n] = rsqrtf(fmaxf(rc0 - gc0 + 1.f, 1.f));
  d_c1[n] = rsqrtf(fmaxf(rc1 - gc1 + 1.f, 1.f));
  float cmr = 0.5f * (rc0 + rc1), cmg = 0.5f * (gc0 + gc1);
  float g0 = gd0 + cmg; gP_dd0[n] = g0;
  d_dd0[n] = rsqrtf(fmaxf(rd0 + cmr - g0 + 1.f, 1.f));
  float g1 = gd1 + cmg; gP_dd1[n] = g1;
  d_dd1[n] = rsqrtf(fmaxf(rd1 + cmr - g1 + 1.f, 1.f));
  float w0 = wb[0], w1 = wb[1];
  float rt = w0 * cmr + w1 * 0.5f * (rd0 + rd1);
  float gt = w0 * cmg + w1 * 0.5f * (gd0 + gd1);
  gP_A1[n] = 2.f * gt;
  d_A1[n] = rsqrtf(fmaxf(rt + cs_tmp[n] - 2.f * gt + 1.f, 1.f));
}

__global__ __launch_bounds__(256) void k_dA2(const float* __restrict__ rs,
                                             const float* __restrict__ gP,
                                             float* __restrict__ dvec) {
  int n = blockIdx.x * 256 + threadIdx.x;
  dvec[n] = rsqrtf(fmaxf(rs[n] - gP[n] + 1.f, 1.f));
}

// ---------------------------------------------------------------------------
// prepB: X [K][C] fp32 (optional per-k scale) -> Bt hi/lo bf16 [C][K]
// ---------------------------------------------------------------------------
__global__ __launch_bounds__(256) void k_prepB(const float* __restrict__ X,
                                               const float* __restrict__ scale,
                                               unsigned short* __restrict__ Bh,
                                               unsigned short* __restrict__ Bl,
                                               int K, int C) {
  __shared__ float t[64][65];
  int kb = blockIdx.x * 64, cb = blockIdx.y * 64;
  int lane = threadIdx.x & 63, w = threadIdx.x >> 6;
  for (int i = 0; i < 16; ++i) {
    int kk = w * 16 + i;
    float s = scale ? scale[kb + kk] : 1.f;
    t[kk][lane] = X[(size_t)(kb + kk) * C + cb + lane] * s;
  }
  __syncthreads();
  for (int i = 0; i < 16; ++i) {
    int cc = w * 16 + i;
    float v = t[lane][cc];
    unsigned short h, l;
    split1(v, h, l);
    size_t o = (size_t)(cb + cc) * K + kb + lane;
    Bh[o] = h; Bl[o] = l;
  }
}

// ---------------------------------------------------------------------------
// Split-bf16 MFMA GEMM: C[M=4096, Nc] += A[4096, K] @ Bt^T  (atomicAdd fp32)
// A modes: 0 = fp32; 1 = fp32 d + 0.5*(c0+c1); 2 = pre-split bf16 pair
// Block: 256 thr = 4 waves (2x2), block tile 64x128, wave tile 32x64.
// grid.x = NB*KS  (nb = x%NB, kb = x/NB), grid.y = 64 (m blocks)
// ---------------------------------------------------------------------------
template <int AMODE>
__global__ __launch_bounds__(256) void k_mm(
    const float* __restrict__ A0, const float* __restrict__ Ax0,
    const float* __restrict__ Ax1, const unsigned short* __restrict__ Abh,
    const unsigned short* __restrict__ Abl, const unsigned short* __restrict__ Bth,
    const unsigned short* __restrict__ Btl, float* __restrict__ C,
    int Nc, int K, int Kc, int NB) {
  int nb = blockIdx.x % NB, kb = blockIdx.x / NB;
  int w = threadIdx.x >> 6, lane = threadIdx.x & 63;
  int wm = w >> 1, wn = w & 1;
  int m0 = blockIdx.y * 64 + wm * 32;
  int n0 = nb * 128 + wn * 64;
  if (n0 >= Nc) return;
  int k0 = kb * Kc;
  int lr = lane & 15, lk = (lane >> 4) * 8;

  const float* apf[2];
  const unsigned short *aph[2], *apl[2];
  const unsigned short *bph[4], *bpl[4];
  size_t koff = (size_t)k0 + lk;
#pragma unroll
  for (int i = 0; i < 2; ++i) {
    size_t r = (size_t)(m0 + i * 16 + lr) * K + koff;
    if constexpr (AMODE == 2) { aph[i] = Abh + r; apl[i] = Abl + r; }
    else apf[i] = A0 + r;
  }
#pragma unroll
  for (int j = 0; j < 4; ++j) {
    size_t r = (size_t)(n0 + j * 16 + lr) * K + koff;
    bph[j] = Bth + r; bpl[j] = Btl + r;
  }

  f32x4 acc[2][4] = {};
  for (int kk = 0; kk < Kc; kk += 32) {
    bf16x8 ah[2], al[2];
#pragma unroll
    for (int i = 0; i < 2; ++i) {
      if constexpr (AMODE == 0) {
        float f[8];
        *(float4*)(f) = *(const float4*)(apf[i] + kk);
        *(float4*)(f + 4) = *(const float4*)(apf[i] + kk + 4);
        split8(f, ah[i], al[i]);
      } else if constexpr (AMODE == 1) {
        size_t off = (apf[i] - A0) + kk;
        float4 xa = *(const float4*)(A0 + off), xb = *(const float4*)(A0 + off + 4);
        float4 ya = *(const float4*)(Ax0 + off), yb = *(const float4*)(Ax0 + off + 4);
        float4 za = *(const float4*)(Ax1 + off), zb = *(const float4*)(Ax1 + off + 4);
        float f[8] = {xa.x + 0.5f * (ya.x + za.x), xa.y + 0.5f * (ya.y + za.y),
                      xa.z + 0.5f * (ya.z + za.z), xa.w + 0.5f * (ya.w + za.w),
                      xb.x + 0.5f * (yb.x + zb.x), xb.y + 0.5f * (yb.y + zb.y),
                      xb.z + 0.5f * (yb.z + zb.z), xb.w + 0.5f * (yb.w + zb.w)};
        split8(f, ah[i], al[i]);
      } else {
        ah[i] = *(const bf16x8*)(aph[i] + kk);
        al[i] = *(const bf16x8*)(apl[i] + kk);
      }
    }
#pragma unroll
    for (int j = 0; j < 4; ++j) {
      bf16x8 bh = *(const bf16x8*)(bph[j] + kk);
      bf16x8 bl = *(const bf16x8*)(bpl[j] + kk);
#pragma unroll
      for (int i = 0; i < 2; ++i) {
        acc[i][j] = __builtin_amdgcn_mfma_f32_16x16x32_bf16(ah[i], bh, acc[i][j], 0, 0, 0);
        acc[i][j] = __builtin_amdgcn_mfma_f32_16x16x32_bf16(ah[i], bl, acc[i][j], 0, 0, 0);
        acc[i][j] = __builtin_amdgcn_mfma_f32_16x16x32_bf16(al[i], bh, acc[i][j], 0, 0, 0);
      }
    }
  }
  int rr = (lane >> 4) * 4;
#pragma unroll
  for (int i = 0; i < 2; ++i)
#pragma unroll
    for (int j = 0; j < 4; ++j) {
      int col = n0 + j * 16 + lr;
#pragma unroll
      for (int r = 0; r < 4; ++r) {
        int row = m0 + i * 16 + rr + r;
        atomicAdd(&C[(size_t)row * Nc + col], acc[i][j][r]);
      }
    }
}

// ---------------------------------------------------------------------------
// Dual cosine Gram GEMM + A2 epilogue:
//   A2 = 0.125*(w0*relu(Cc@Cc^T) + w1*relu(Cd@Cd^T)), written as split-bf16,
//   plus rowsums (atomic) and raw diagonal.
// grid (32, 64); K = 1024.
// ---------------------------------------------------------------------------
__global__ __launch_bounds__(256) void k_cos(
    const unsigned short* __restrict__ Ch, const unsigned short* __restrict__ Cl,
    const unsigned short* __restrict__ Dh, const unsigned short* __restrict__ Dl,
    const float* __restrict__ wb, float* __restrict__ rs, float* __restrict__ gP,
    unsigned short* __restrict__ A2h, unsigned short* __restrict__ A2l) {
  int w = threadIdx.x >> 6, lane = threadIdx.x & 63;
  int wm = w >> 1, wn = w & 1;
  int m0 = blockIdx.y * 64 + wm * 32;
  int n0 = blockIdx.x * 128 + wn * 64;
  int lr = lane & 15, lk = (lane >> 4) * 8;
  const unsigned short *cah[2], *cal[2], *dah[2], *dal[2];
  const unsigned short *cbh[4], *cbl[4], *dbh[4], *dbl[4];
#pragma unroll
  for (int i = 0; i < 2; ++i) {
    size_t r = (size_t)(m0 + i * 16 + lr) * 1024 + lk;
    cah[i] = Ch + r; cal[i] = Cl + r; dah[i] = Dh + r; dal[i] = Dl + r;
  }
#pragma unroll
  for (int j = 0; j < 4; ++j) {
    size_t r = (size_t)(n0 + j * 16 + lr) * 1024 + lk;
    cbh[j] = Ch + r; cbl[j] = Cl + r; dbh[j] = Dh + r; dbl[j] = Dl + r;
  }
  f32x4 ac[2][4] = {}, ad[2][4] = {};
  for (int kk = 0; kk < 1024; kk += 32) {
    bf16x8 ah[2], al[2];
#pragma unroll
    for (int i = 0; i < 2; ++i) { ah[i] = *(const bf16x8*)(cah[i] + kk); al[i] = *(const bf16x8*)(cal[i] + kk); }
#pragma unroll
    for (int j = 0; j < 4; ++j) {
      bf16x8 bh = *(const bf16x8*)(cbh[j] + kk);
      bf16x8 bl = *(const bf16x8*)(cbl[j] + kk);
#pragma unroll
      for (int i = 0; i < 2; ++i) {
        ac[i][j] = __builtin_amdgcn_mfma_f32_16x16x32_bf16(ah[i], bh, ac[i][j], 0, 0, 0);
        ac[i][j] = __builtin_amdgcn_mfma_f32_16x16x32_bf16(ah[i], bl, ac[i][j], 0, 0, 0);
        ac[i][j] = __builtin_amdgcn_mfma_f32_16x16x32_bf16(al[i], bh, ac[i][j], 0, 0, 0);
      }
    }
#pragma unroll
    for (int i = 0; i < 2; ++i) { ah[i] = *(const bf16x8*)(dah[i] + kk); al[i] = *(const bf16x8*)(dal[i] + kk); }
#pragma unroll
    for (int j = 0; j < 4; ++j) {
      bf16x8 bh = *(const bf16x8*)(dbh[j] + kk);
      bf16x8 bl = *(const bf16x8*)(dbl[j] + kk);
#pragma unroll
      for (int i = 0; i < 2; ++i) {
        ad[i][j] = __builtin_amdgcn_mfma_f32_16x16x32_bf16(ah[i], bh, ad[i][j], 0, 0, 0);
        ad[i][j] = __builtin_amdgcn_mfma_f32_16x16x32_bf16(ah[i], bl, ad[i][j], 0, 0, 0);
        ad[i][j] = __builtin_amdgcn_mfma_f32_16x16x32_bf16(al[i], bh, ad[i][j], 0, 0, 0);
      }
    }
  }
  float w0 = wb[0] * 0.125f, w1 = wb[1] * 0.125f;
  int rr = (lane >> 4) * 4;
#pragma unroll
  for (int i = 0; i < 2; ++i) {
#pragma unroll
    for (int r = 0; r < 4; ++r) {
      int row = m0 + i * 16 + rr + r;
      float p = 0.f;
#pragma unroll
      for (int j = 0; j < 4; ++j) {
        int col = n0 + j * 16 + lr;
        float v = w0 * fmaxf(ac[i][j][r], 0.f) + w1 * fmaxf(ad[i][j][r], 0.f);
        p += v;
        unsigned short h, l;
        split1(v, h, l);
        size_t o = (size_t)row * 4096 + col;
        A2h[o] = h; A2l[o] = l;
        if (row == col) gP[row] = v;
      }
      p += __shfl_xor(p, 1); p += __shfl_xor(p, 2);
      p += __shfl_xor(p, 4); p += __shfl_xor(p, 8);
      if (lr == 0) atomicAdd(&rs[row], p);
    }
  }
}

// ---------------------------------------------------------------------------
// Epilogues
// ---------------------------------------------------------------------------
// GCN prop: out = relu(dn*(acc + (1-diag)*dn*xw) + bias), [4096][256]
__global__ __launch_bounds__(256) void k_ep_prop(
    const float* __restrict__ acc, const float* __restrict__ xw,
    const float* __restrict__ dvec, const float* __restrict__ diag,
    const float* __restrict__ bias, float* __restrict__ out) {
  int idx = blockIdx.x * 256 + threadIdx.x;
  int i = idx * 4, row = i >> 8, c = i & 255;
  float4 a = *(const float4*)(acc + i);
  float4 x = *(const float4*)(xw + i);
  float4 b = *(const float4*)(bias + c);
  float dn = dvec[row], dfix = (1.f - diag[row]) * dn;
  float4 o;
  o.x = fmaxf(dn * (a.x + dfix * x.x) + b.x, 0.f);
  o.y = fmaxf(dn * (a.y + dfix * x.y) + b.y, 0.f);
  o.z = fmaxf(dn * (a.z + dfix * x.z) + b.z, 0.f);
  o.w = fmaxf(dn * (a.w + dfix * x.w) + b.w, 0.f);
  *(float4*)(out + i) = o;
}

// head epilogue in-place on [4096][64]: relu(+bias), optional sigmoid
template <int SIG>
__global__ __launch_bounds__(256) void k_ep_head(float* __restrict__ io,
                                                 const float* __restrict__ bias) {
  int idx = blockIdx.x * 256 + threadIdx.x;
  int i = idx * 4, c = i & 63;
  float4 a = *(const float4*)(io + i);
  float4 b = *(const float4*)(bias + c);
  float4 o;
  o.x = fmaxf(a.x + b.x, 0.f); o.y = fmaxf(a.y + b.y, 0.f);
  o.z = fmaxf(a.z + b.z, 0.f); o.w = fmaxf(a.w + b.w, 0.f);
  if constexpr (SIG) {
    o.x = 1.f / (1.f + expf(-o.x)); o.y = 1.f / (1.f + expf(-o.y));
    o.z = 1.f / (1.f + expf(-o.z)); o.w = 1.f / (1.f + expf(-o.w));
  }
  *(float4*)(io + i) = o;
}

// ---------------------------------------------------------------------------
// Attention score accumulation
// ---------------------------------------------------------------------------
__global__ __launch_bounds__(256) void k_att(
    const float* __restrict__ z0, const float* __restrict__ z1,
    const float* __restrict__ z2, const float* __restrict__ z3,
    const float* __restrict__ W1, const float* __restrict__ b1,
    const float* __restrict__ w2, float* __restrict__ s_out) {
  int k = blockIdx.y;
  const float* z = (k == 0) ? z0 : (k == 1) ? z1 : (k == 2) ? z2 : z3;
  int wave = threadIdx.x >> 6, lane = threadIdx.x & 63;
  float total = 0.f;
  for (int n = blockIdx.x * 4 + wave; n < 4096; n += gridDim.x * 4) {
    float s0 = 0.f, s1 = 0.f;
    const float* zr = z + (size_t)n * 256;
    for (int h = 0; h < 256; ++h) {
      float zv = zr[h];
      s0 += zv * W1[h * 128 + lane];
      s1 += zv * W1[h * 128 + 64 + lane];
    }
    float v = tanhf(s0 + b1[lane]) * w2[lane] + tanhf(s1 + b1[64 + lane]) * w2[64 + lane];
    v = wave_reduce_sum(v);
    if (lane == 0) total += v;
  }
  if (lane == 0) atomicAdd(&s_out[k], total);
}

__global__ void k_beta(const float* __restrict__ s, float* __restrict__ bb) {
  if (threadIdx.x == 0 && blockIdx.x == 0) {
    const float inv = 1.f / 4096.f;
    float c0 = s[0] * inv, c1 = s[1] * inv;
    float m = fmaxf(c0, c1);
    float e0 = expf(c0 - m), e1 = expf(c1 - m);
    float is = 1.f / (e0 + e1);
    bb[0] = e0 * is; bb[1] = e1 * is;
    float d0 = s[2] * inv, d1 = s[3] * inv, d2 = s[4] * inv, d3 = s[5] * inv;
    float md = fmaxf(fmaxf(d0, d1), fmaxf(d2, d3));
    float f0 = expf(d0 - md), f1 = expf(d1 - md), f2 = expf(d2 - md), f3 = expf(d3 - md);
    float id = 1.f / (f0 + f1 + f2 + f3);
    bb[2] = f0 * id; bb[3] = f1 * id; bb[4] = f2 * id; bb[5] = f3 * id;
  }
}

__global__ __launch_bounds__(256) void k_agg(
    const float* __restrict__ cr0, const float* __restrict__ cr1,
    const float* __restrict__ dr0, const float* __restrict__ dr1,
    const float* __restrict__ bb, float* __restrict__ cagg, float* __restrict__ dagg) {
  size_t i = ((size_t)blockIdx.x * 256 + threadIdx.x) * 4;
  float4 a = *(const float4*)(cr0 + i);
  float4 b = *(const float4*)(cr1 + i);
  float4 c = *(const float4*)(dr0 + i);
  float4 d = *(const float4*)(dr1 + i);
  float bc0 = bb[0], bc1 = bb[1], bd0 = bb[2], bd1 = bb[3], bd2 = bb[4], bd3 = bb[5];
  float4 ca, da;
  ca.x = bc0 * a.x + bc1 * b.x; ca.y = bc0 * a.y + bc1 * b.y;
  ca.z = bc0 * a.z + bc1 * b.z; ca.w = bc0 * a.w + bc1 * b.w;
  da.x = bd0 * a.x + bd1 * b.x + bd2 * c.x + bd3 * d.x;
  da.y = bd0 * a.y + bd1 * b.y + bd2 * c.y + bd3 * d.y;
  da.z = bd0 * a.z + bd1 * b.z + bd2 * c.z + bd3 * d.z;
  da.w = bd0 * a.w + bd1 * b.w + bd2 * c.w + bd3 * d.w;
  *(float4*)(cagg + i) = ca;
  *(float4*)(dagg + i) = da;
}

// cn rows -> split bf16 [4096][1024]
__global__ __launch_bounds__(256) void k_cn(const float* __restrict__ mu,
                                            const float* __restrict__ Wt,
                                            unsigned short* __restrict__ Chh,
                                            unsigned short* __restrict__ Cll) {
  int g = blockIdx.x * 4 + (threadIdx.x >> 6);
  int lane = threadIdx.x & 63;
  int n = g >> 4, p = g & 15;
  float v = mu[(size_t)n * 64 + lane] * Wt[p * 64 + lane];
  float ss = v * v;
#pragma unroll
  for (int off = 32; off > 0; off >>= 1) ss += __shfl_xor(ss, off);
  float nrm = fmaxf(sqrtf(ss), 1e-12f);
  float r = v / nrm;
  unsigned short h, l;
  split1(r, h, l);
  size_t o = (size_t)n * 1024 + p * 64 + lane;
  Chh[o] = h; Cll[o] = l;
}

__global__ __launch_bounds__(256) void k_gather(
    const int* __restrict__ xs, const float* __restrict__ U1, const float* __restrict__ U2,
    const float* __restrict__ V1, const float* __restrict__ V2, float* __restrict__ out) {
  int b = blockIdx.x, j = threadIdx.x;
  int row = xs[b];
  size_t r = (size_t)row * 256;
  out[(size_t)b * 512 + j] = 0.5f * (U1[r + j] + U2[r + j]);
  out[(size_t)b * 512 + 256 + j] = 0.5f * (V1[r + j] + V2[r + j]);
}

// ---------------------------------------------------------------------------
extern "C" void kernel_launch(void* const* d_in, const int* in_sizes, int n_in,
                              void* d_out, int out_size, void* d_ws, size_t ws_size,
                              hipStream_t stream) {
  const float* c0adj = (const float*)d_in[0];
  const float* c1adj = (const float*)d_in[1];
  const float* d0adj = (const float*)d_in[2];
  const float* d1adj = (const float*)d_in[3];
  const float* feats = (const float*)d_in[4];
  const float* W_comm = (const float*)d_in[5];
  const float* b_comm = (const float*)d_in[6];
  const float* W_diff = (const float*)d_in[7];
  const float* b_diff = (const float*)d_in[8];
  const float* W_catt1 = (const float*)d_in[9];
  const float* b_catt1 = (const float*)d_in[10];
  const float* w_catt2 = (const float*)d_in[11];
  const float* W_datt1 = (const float*)d_in[12];
  const float* b_datt1 = (const float*)d_in[13];
  const float* w_datt2 = (const float*)d_in[14];
  const float* W_mu_c = (const float*)d_in[15];
  const float* b_mu_c = (const float*)d_in[16];
  const float* W_var_c = (const float*)d_in[17];
  const float* b_var_c = (const float*)d_in[18];
  const float* W_mu_d = (const float*)d_in[19];
  const float* b_mu_d = (const float*)d_in[20];
  const float* W_var_d = (const float*)d_in[21];
  const float* b_var_d = (const float*)d_in[22];
  const float* W_z1_1 = (const float*)d_in[23];
  const float* b_z1_1 = (const float*)d_in[24];
  const float* W_z1_2 = (const float*)d_in[25];
  const float* b_z1_2 = (const float*)d_in[26];
  const float* wb_z1 = (const float*)d_in[27];
  const float* Wt_c = (const float*)d_in[28];
  const float* Wt_d = (const float*)d_in[29];
  const float* W_z2_1 = (const float*)d_in[30];
  const float* b_z2_1 = (const float*)d_in[31];
  const float* W_z2_2 = (const float*)d_in[32];
  const float* b_z2_2 = (const float*)d_in[33];
  const float* wb_z2 = (const float*)d_in[34];
  const int* xs = (const int*)d_in[35];

  float* out = (float*)d_out;
  float* out_muc = out + 65536;
  float* out_varc = out + 327680;
  float* out_mud = out + 589824;
  float* out_vard = out + 851968;

  float* ws = (float*)d_ws;
  const size_t M1 = 1048576;  // 4096*256 floats (4 MB)
  float* xw_comm = ws + 0 * M1;
  float* xw_diff = ws + 1 * M1;
  float* xw_z1 = ws + 2 * M1;
  float* xw_z2 = ws + 3 * M1;
  float* cr0 = ws + 4 * M1;
  float* cr1 = ws + 5 * M1;
  float* dr0 = ws + 6 * M1;
  float* dr1 = ws + 7 * M1;
  float* u1 = ws + 8 * M1;
  float* u2 = ws + 9 * M1;
  float* v1 = ws + 10 * M1;
  float* v2 = ws + 11 * M1;
  float* uw = ws + 12 * M1;
  float* cagg = ws + 13 * M1;
  float* dagg = ws + 14 * M1;
  float* accb = ws + 15 * M1;
  unsigned short* Bth = (unsigned short*)(ws + 16 * M1);
  unsigned short* Btl = (unsigned short*)(ws + 17 * M1);
  unsigned short* Cch = (unsigned short*)(ws + 18 * M1);  // 2 M1 each
  unsigned short* Ccl = (unsigned short*)(ws + 20 * M1);
  unsigned short* Cdh = (unsigned short*)(ws + 22 * M1);
  unsigned short* Cdl = (unsigned short*)(ws + 24 * M1);
  unsigned short* A1h = (unsigned short*)(ws + 26 * M1);  // 8 M1 each
  unsigned short* A1l = (unsigned short*)(ws + 34 * M1);
  float* tmpb = ws + 42 * M1;                              // 16 M1 fp32
  unsigned short* A2h = (unsigned short*)(ws + 42 * M1);   // overlays tmpb (tmp dead by then)
  unsigned short* A2l = (unsigned short*)(ws + 50 * M1);
  float* vecs = ws + 58 * M1;
#define VV(i) (vecs + (size_t)(i) * 4096)
  float* rs_c0 = VV(0); float* rs_c1 = VV(1); float* rs_d0 = VV(2); float* rs_d1 = VV(3);
  float* dg_c0 = VV(4); float* dg_c1 = VV(5); float* dg_d0 = VV(6); float* dg_d1 = VV(7);
  float* cs_tmp = VV(8); float* rs_A2 = VV(9);
  float* d_c0 = VV(10); float* d_c1 = VV(11); float* d_dd0 = VV(12); float* d_dd1 = VV(13);
  float* d_A1 = VV(14); float* d_A2 = VV(15);
  float* gP_dd0 = VV(16); float* gP_dd1 = VV(17); float* gP_A1 = VV(18); float* gP_A2 = VV(19);
  float* satt = VV(20);
  float* beta = satt + 8;

  hipMemsetAsync(cs_tmp, 0, 2 * 4096 * sizeof(float), stream);  // cs_tmp + rs_A2
  hipMemsetAsync(satt, 0, 64, stream);
  hipMemsetAsync(xw_comm, 0, 4 * M1 * sizeof(float), stream);   // xw_* (atomic targets)
  hipMemsetAsync(out_muc, 0, 4 * 262144 * sizeof(float), stream);  // head atomic targets

  // adjacency pass
  k_rowsums<<<256, 256, 0, stream>>>(c0adj, c1adj, d0adj, d1adj, wb_z1, tmpb,
                                     rs_c0, rs_c1, rs_d0, rs_d1, dg_c0, dg_c1, dg_d0, dg_d1);
  k_colsum<<<dim3(16, 32), 256, 0, stream>>>(tmpb, cs_tmp);
  k_fin<<<16, 256, 0, stream>>>(rs_c0, rs_c1, rs_d0, rs_d1, dg_c0, dg_c1, dg_d0, dg_d1,
                                cs_tmp, wb_z1, d_c0, d_c1, d_dd0, d_dd1, d_A1,
                                gP_dd0, gP_dd1, gP_A1);
  k_addT<<<dim3(64, 64), 256, 0, stream>>>(tmpb, A1h, A1l);

  // ---- feats @ W  (4x): K=512, Nc=256, KS=4 (Kc=128) ----
  const float* Wf[4] = {W_comm, W_diff, W_z1_1, W_z2_1};
  float* xwf[4] = {xw_comm, xw_diff, xw_z1, xw_z2};
  for (int t = 0; t < 4; ++t) {
    k_prepB<<<dim3(8, 4), 256, 0, stream>>>(Wf[t], nullptr, Bth, Btl, 512, 256);
    k_mm<0><<<dim3(2 * 4, 64), 256, 0, stream>>>(feats, nullptr, nullptr, nullptr, nullptr,
                                                 Bth, Btl, xwf[t], 256, 512, 128, 2);
  }

  // ---- GCN propagations: K=4096, Nc=256, KS=8 (Kc=512), grid (16,64) ----
  // comm reps
  k_prepB<<<dim3(64, 4), 256, 0, stream>>>(xw_comm, d_c0, Bth, Btl, 4096, 256);
  hipMemsetAsync(accb, 0, M1 * sizeof(float), stream);
  k_mm<0><<<dim3(16, 64), 256, 0, stream>>>(c0adj, nullptr, nullptr, nullptr, nullptr,
                                            Bth, Btl, accb, 256, 4096, 512, 2);
  k_ep_prop<<<1024, 256, 0, stream>>>(accb, xw_comm, d_c0, dg_c0, b_comm, cr0);

  k_prepB<<<dim3(64, 4), 256, 0, stream>>>(xw_comm, d_c1, Bth, Btl, 4096, 256);
  hipMemsetAsync(accb, 0, M1 * sizeof(float), stream);
  k_mm<0><<<dim3(16, 64), 256, 0, stream>>>(c1adj, nullptr, nullptr, nullptr, nullptr,
                                            Bth, Btl, accb, 256, 4096, 512, 2);
  k_ep_prop<<<1024, 256, 0, stream>>>(accb, xw_comm, d_c1, dg_c1, b_comm, cr1);

  // diff reps (A = d_i + 0.5*(c0+c1))
  k_prepB<<<dim3(64, 4), 256, 0, stream>>>(xw_diff, d_dd0, Bth, Btl, 4096, 256);
  hipMemsetAsync(accb, 0, M1 * sizeof(float), stream);
  k_mm<1><<<dim3(16, 64), 256, 0, stream>>>(d0adj, c0adj, c1adj, nullptr, nullptr,
                                            Bth, Btl, accb, 256, 4096, 512, 2);
  k_ep_prop<<<1024, 256, 0, stream>>>(accb, xw_diff, d_dd0, gP_dd0, b_diff, dr0);

  k_prepB<<<dim3(64, 4), 256, 0, stream>>>(xw_diff, d_dd1, Bth, Btl, 4096, 256);
  hipMemsetAsync(accb, 0, M1 * sizeof(float), stream);
  k_mm<1><<<dim3(16, 64), 256, 0, stream>>>(d1adj, c0adj, c1adj, nullptr, nullptr,
                                            Bth, Btl, accb, 256, 4096, 512, 2);
  k_ep_prop<<<1024, 256, 0, stream>>>(accb, xw_diff, d_dd1, gP_dd1, b_diff, dr1);

  // z1 branch: U1
  k_prepB<<<dim3(64, 4), 256, 0, stream>>>(xw_z1, d_A1, Bth, Btl, 4096, 256);
  hipMemsetAsync(accb, 0, M1 * sizeof(float), stream);
  k_mm<2><<<dim3(16, 64), 256, 0, stream>>>(nullptr, nullptr, nullptr, A1h, A1l,
                                            Bth, Btl, accb, 256, 4096, 512, 2);
  k_ep_prop<<<1024, 256, 0, stream>>>(accb, xw_z1, d_A1, gP_A1, b_z1_1, u1);
  // uw = U1 @ W_z1_2 (K=256, KS=2)
  k_prepB<<<dim3(4, 4), 256, 0, stream>>>(W_z1_2, nullptr, Bth, Btl, 256, 256);
  hipMemsetAsync(uw, 0, M1 * sizeof(float), stream);
  k_mm<0><<<dim3(2 * 2, 64), 256, 0, stream>>>(u1, nullptr, nullptr, nullptr, nullptr,
                                               Bth, Btl, uw, 256, 256, 128, 2);
  // U2
  k_prepB<<<dim3(64, 4), 256, 0, stream>>>(uw, d_A1, Bth, Btl, 4096, 256);
  hipMemsetAsync(accb, 0, M1 * sizeof(float), stream);
  k_mm<2><<<dim3(16, 64), 256, 0, stream>>>(nullptr, nullptr, nullptr, A1h, A1l,
                                            Bth, Btl, accb, 256, 4096, 512, 2);
  k_ep_prop<<<1024, 256, 0, stream>>>(accb, uw, d_A1, gP_A1, b_z1_2, u2);

  // attention
  k_att<<<dim3(64, 2), 256, 0, stream>>>(cr0, cr1, cr0, cr0, W_catt1, b_catt1, w_catt2, satt);
  k_att<<<dim3(64, 4), 256, 0, stream>>>(cr0, cr1, dr0, dr1, W_datt1, b_datt1, w_datt2, satt + 2);
  k_beta<<<1, 64, 0, stream>>>(satt, beta);
  k_agg<<<1024, 256, 0, stream>>>(cr0, cr1, dr0, dr1, beta, cagg, dagg);

  // heads: K=256, Nc=64, KS=4 (Kc=64), NB=1, atomic straight into d_out regions
  const float* Wh[4] = {W_mu_c, W_var_c, W_mu_d, W_var_d};
  const float* bh[4] = {b_mu_c, b_var_c, b_mu_d, b_var_d};
  const float* ah[4] = {cagg, cagg, dagg, dagg};
  float* oh[4] = {out_muc, out_varc, out_mud, out_vard};
  for (int t = 0; t < 4; ++t) {
    k_prepB<<<dim3(4, 1), 256, 0, stream>>>(Wh[t], nullptr, Bth, Btl, 256, 64);
    k_mm<0><<<dim3(1 * 4, 64), 256, 0, stream>>>(ah[t], nullptr, nullptr, nullptr, nullptr,
                                                 Bth, Btl, oh[t], 64, 256, 64, 1);
    if (t & 1)
      k_ep_head<1><<<256, 256, 0, stream>>>(oh[t], bh[t]);
    else
      k_ep_head<0><<<256, 256, 0, stream>>>(oh[t], bh[t]);
  }

  // cosine contexts (split bf16)
  k_cn<<<16384, 256, 0, stream>>>(out_muc, Wt_c, Cch, Ccl);
  k_cn<<<16384, 256, 0, stream>>>(out_mud, Wt_d, Cdh, Cdl);

  // A2 = 0.125*(w0*relu(Cc@Cc^T) + w1*relu(Cd@Cd^T)) -> bf16 pair + rowsums + diag
  k_cos<<<dim3(32, 64), 256, 0, stream>>>(Cch, Ccl, Cdh, Cdl, wb_z2, rs_A2, gP_A2, A2h, A2l);
  k_dA2<<<16, 256, 0, stream>>>(rs_A2, gP_A2, d_A2);

  // z2 branch: V1
  k_prepB<<<dim3(64, 4), 256, 0, stream>>>(xw_z2, d_A2, Bth, Btl, 4096, 256);
  hipMemsetAsync(accb, 0, M1 * sizeof(float), stream);
  k_mm<2><<<dim3(16, 64), 256, 0, stream>>>(nullptr, nullptr, nullptr, A2h, A2l,
                                            Bth, Btl, accb, 256, 4096, 512, 2);
  k_ep_prop<<<1024, 256, 0, stream>>>(accb, xw_z2, d_A2, gP_A2, b_z2_1, v1);
  // vw = V1 @ W_z2_2
  k_prepB<<<dim3(4, 4), 256, 0, stream>>>(W_z2_2, nullptr, Bth, Btl, 256, 256);
  hipMemsetAsync(uw, 0, M1 * sizeof(float), stream);
  k_mm<0><<<dim3(2 * 2, 64), 256, 0, stream>>>(v1, nullptr, nullptr, nullptr, nullptr,
                                               Bth, Btl, uw, 256, 256, 128, 2);
  // V2
  k_prepB<<<dim3(64, 4), 256, 0, stream>>>(uw, d_A2, Bth, Btl, 4096, 256);
  hipMemsetAsync(accb, 0, M1 * sizeof(float), stream);
  k_mm<2><<<dim3(16, 64), 256, 0, stream>>>(nullptr, nullptr, nullptr, A2h, A2l,
                                            Bth, Btl, accb, 256, 4096, 512, 2);
  k_ep_prop<<<1024, 256, 0, stream>>>(accb, uw, d_A2, gP_A2, b_z2_2, v2);

  // h[xs]
  k_gather<<<128, 256, 0, stream>>>(xs, u1, u2, v1, v2, out);
}

// Round 3
// 1434.686 us; speedup vs baseline: 3.4935x; 1.7647x over previous
//
#include <hip/hip_runtime.h>
#include <math.h>

// N=4096, F_IN=512, Z=256, H=256, E=64, ATT=128, NPER=16, B=128
using f32x4 = __attribute__((ext_vector_type(4))) float;
using bf16x8 = __attribute__((ext_vector_type(8))) short;
#define MFMA16 __builtin_amdgcn_mfma_f32_16x16x32_bf16

__device__ __forceinline__ float wave_reduce_sum(float v) {
#pragma unroll
  for (int off = 32; off > 0; off >>= 1) v += __shfl_down(v, off);
  return v;
}

__device__ __forceinline__ unsigned short f2bf_rne(float x) {
  unsigned int u = __float_as_uint(x);
  unsigned int r = u + 0x7FFFu + ((u >> 16) & 1u);
  return (unsigned short)(r >> 16);
}
__device__ __forceinline__ void split1(float x, unsigned short& h, unsigned short& l) {
  unsigned int u = __float_as_uint(x);
  h = (unsigned short)(u >> 16);
  float rem = x - __uint_as_float(u & 0xFFFF0000u);
  l = f2bf_rne(rem);
}
__device__ __forceinline__ void split8(const float* f, bf16x8& h, bf16x8& l) {
#pragma unroll
  for (int i = 0; i < 8; ++i) {
    unsigned short hh, ll;
    split1(f[i], hh, ll);
    h[i] = (short)hh;
    l[i] = (short)ll;
  }
}
__device__ __forceinline__ float b2f(short u) {
  return __uint_as_float(((unsigned int)(unsigned short)u) << 16);
}

// ---------------------------------------------------------------------------
// Adjacency pass: row sums, diagonals, tmp = 0.5*w0*(c0+c1) + 0.5*w1*(d0+d1)
// ---------------------------------------------------------------------------
__global__ __launch_bounds__(256) void k_rowsums(
    const float* __restrict__ c0, const float* __restrict__ c1,
    const float* __restrict__ d0, const float* __restrict__ d1,
    const float* __restrict__ wb, float* __restrict__ tmp,
    float* __restrict__ rs_c0, float* __restrict__ rs_c1,
    float* __restrict__ rs_d0, float* __restrict__ rs_d1,
    float* __restrict__ dg_c0, float* __restrict__ dg_c1,
    float* __restrict__ dg_d0, float* __restrict__ dg_d1) {
  int wave = threadIdx.x >> 6, lane = threadIdx.x & 63;
  float hw0 = 0.5f * wb[0], hw1 = 0.5f * wb[1];
  int rbase = blockIdx.x * 16 + wave * 4;
  for (int i = 0; i < 4; ++i) {
    int row = rbase + i;
    const float* pc0 = c0 + (size_t)row * 4096;
    const float* pc1 = c1 + (size_t)row * 4096;
    const float* pd0 = d0 + (size_t)row * 4096;
    const float* pd1 = d1 + (size_t)row * 4096;
    float* pt = tmp + (size_t)row * 4096;
    float s0 = 0.f, s1 = 0.f, s2 = 0.f, s3 = 0.f;
    for (int ct = 0; ct < 64; ++ct) {
      int col = ct * 64 + lane;
      float a = pc0[col], b = pc1[col], e = pd0[col], f = pd1[col];
      s0 += a; s1 += b; s2 += e; s3 += f;
      pt[col] = hw0 * (a + b) + hw1 * (e + f);
      if (col == row) { dg_c0[row] = a; dg_c1[row] = b; dg_d0[row] = e; dg_d1[row] = f; }
    }
    s0 = wave_reduce_sum(s0); s1 = wave_reduce_sum(s1);
    s2 = wave_reduce_sum(s2); s3 = wave_reduce_sum(s3);
    if (lane == 0) { rs_c0[row] = s0; rs_c1[row] = s1; rs_d0[row] = s2; rs_d1[row] = s3; }
  }
}

__global__ __launch_bounds__(256) void k_colsum(const float* __restrict__ T,
                                                float* __restrict__ cs) {
  int c = blockIdx.x * 256 + threadIdx.x;
  int r0 = blockIdx.y * 128;
  float a = 0.f;
  for (int r = r0; r < r0 + 128; ++r) a += T[(size_t)r * 4096 + c];
  atomicAdd(&cs[c], a);
}

// A1n = d[row]*d[col]*(tmp + tmp^T), written as split-bf16 pair
__global__ __launch_bounds__(256) void k_addTn(const float* __restrict__ T,
                                               const float* __restrict__ dv,
                                               unsigned short* __restrict__ A1h,
                                               unsigned short* __restrict__ A1l) {
  __shared__ float t[64][65];
  int bi = blockIdx.y, bj = blockIdx.x;
  int lane = threadIdx.x & 63, w = threadIdx.x >> 6;
  for (int i = w; i < 64; i += 4)
    t[i][lane] = T[(size_t)(bj * 64 + i) * 4096 + bi * 64 + lane];
  __syncthreads();
  for (int i = w; i < 64; i += 4) {
    int row = bi * 64 + i, col = bj * 64 + lane;
    size_t idx = (size_t)row * 4096 + col;
    float v = (T[idx] + t[lane][i]) * dv[row] * dv[col];
    unsigned short h, l;
    split1(v, h, l);
    A1h[idx] = h; A1l[idx] = l;
  }
}

__global__ __launch_bounds__(256) void k_fin(
    const float* __restrict__ rs_c0, const float* __restrict__ rs_c1,
    const float* __restrict__ rs_d0, const float* __restrict__ rs_d1,
    const float* __restrict__ dg_c0, const float* __restrict__ dg_c1,
    const float* __restrict__ dg_d0, const float* __restrict__ dg_d1,
    const float* __restrict__ cs_tmp, const float* __restrict__ wb,
    float* __restrict__ d_c0, float* __restrict__ d_c1,
    float* __restrict__ d_dd0, float* __restrict__ d_dd1, float* __restrict__ d_A1,
    float* __restrict__ gP_dd0, float* __restrict__ gP_dd1, float* __restrict__ gP_A1) {
  int n = blockIdx.x * 256 + threadIdx.x;
  float rc0 = rs_c0[n], rc1 = rs_c1[n], rd0 = rs_d0[n], rd1 = rs_d1[n];
  float gc0 = dg_c0[n], gc1 = dg_c1[n], gd0 = dg_d0[n], gd1 = dg_d1[n];
  d_c0[n] = rsqrtf(fmaxf(rc0 - gc0 + 1.f, 1.f));
  d_c1[n] = rsqrtf(fmaxf(rc1 - gc1 + 1.f, 1.f));
  float cmr = 0.5f * (rc0 + rc1), cmg = 0.5f * (gc0 + gc1);
  float g0 = gd0 + cmg; gP_dd0[n] = g0;
  d_dd0[n] = rsqrtf(fmaxf(rd0 + cmr - g0 + 1.f, 1.f));
  float g1 = gd1 + cmg; gP_dd1[n] = g1;
  d_dd1[n] = rsqrtf(fmaxf(rd1 + cmr - g1 + 1.f, 1.f));
  float w0 = wb[0], w1 = wb[1];
  float rt = w0 * cmr + w1 * 0.5f * (rd0 + rd1);
  float gt = w0 * cmg + w1 * 0.5f * (gd0 + gd1);
  gP_A1[n] = 2.f * gt;
  d_A1[n] = rsqrtf(fmaxf(rt + cs_tmp[n] - 2.f * gt + 1.f, 1.f));
}

__global__ __launch_bounds__(256) void k_dA2(const float* __restrict__ rs,
                                             const float* __restrict__ gP,
                                             float* __restrict__ dvec) {
  int n = blockIdx.x * 256 + threadIdx.x;
  dvec[n] = rsqrtf(fmaxf(rs[n] - gP[n] + 1.f, 1.f));
}

// ---------------------------------------------------------------------------
// prepB: X [K][C] fp32 -> Bt hi/lo bf16 [C][K]
// ---------------------------------------------------------------------------
__global__ __launch_bounds__(256) void k_prepB(const float* __restrict__ X,
                                               unsigned short* __restrict__ Bh,
                                               unsigned short* __restrict__ Bl,
                                               int K, int C) {
  __shared__ float t[64][65];
  int kb = blockIdx.x * 64, cb = blockIdx.y * 64;
  int lane = threadIdx.x & 63, w = threadIdx.x >> 6;
  for (int i = 0; i < 16; ++i) {
    int kk = w * 16 + i;
    t[kk][lane] = X[(size_t)(kb + kk) * C + cb + lane];
  }
  __syncthreads();
  for (int i = 0; i < 16; ++i) {
    int cc = w * 16 + i;
    float v = t[lane][cc];
    unsigned short h, l;
    split1(v, h, l);
    size_t o = (size_t)(cb + cc) * K + kb + lane;
    Bh[o] = h; Bl[o] = l;
  }
}

// ---------------------------------------------------------------------------
// LDS-staged split-bf16 MFMA GEMM: C[4096,256] += epi(A[4096,K] @ Bt^T)
// AMODE 0: A fp32; 1: A = A0 + 0.5*(Ax0+Ax1) fp32; 2: A split-bf16 pair;
//       3: dual-A heads (waves 0-1 use A0, waves 2-3 use Ax0)
// scale (optional): per-k column scale applied at staging.
// Block: 256 thr = 4 waves; tile 64(M) x 256(N); wave = 64x64.
// grid = (KS, 64); Kc = K/KS. Output via atomicAdd (C pre-zeroed).
// ---------------------------------------------------------------------------
template <int AMODE>
__global__ __launch_bounds__(256) void k_gemm(
    const float* __restrict__ A0, const float* __restrict__ Ax0,
    const float* __restrict__ Ax1,
    const unsigned short* __restrict__ Abh, const unsigned short* __restrict__ Abl,
    const float* __restrict__ scale,
    const unsigned short* __restrict__ Bth, const unsigned short* __restrict__ Btl,
    float* __restrict__ C, int K, int Kc) {
  constexpr int NSLOT = (AMODE == 3) ? 2 : 1;
  __shared__ unsigned char sm[2][NSLOT][8192];  // [buf][slot][64 rows * 128B (hi64|lo64)]
  const int tid = threadIdx.x;
  const int m0 = blockIdx.y * 64;
  const int k0 = blockIdx.x * Kc;
  const int w = tid >> 6, lane = tid & 63;
  const int lr = lane & 15, lk = (lane >> 4) * 8;
  const int n0w = w * 64;
  const int srow = tid >> 2, skp = (tid & 3) * 8;
  const int swz = (srow & 7) << 4;
  const int offh = (srow * 128 + skp * 2) ^ swz;
  const int offl = (srow * 128 + 64 + skp * 2) ^ swz;

  auto stage = [&](int b, int kk) {
    int kg = k0 + kk + skp;
    float f[8];
    if constexpr (AMODE == 2) {
      bf16x8 h = *(const bf16x8*)(Abh + (size_t)(m0 + srow) * K + kg);
      bf16x8 l = *(const bf16x8*)(Abl + (size_t)(m0 + srow) * K + kg);
      if (scale) {
#pragma unroll
        for (int i = 0; i < 8; ++i) f[i] = (b2f(h[i]) + b2f(l[i])) * scale[kg + i];
        bf16x8 hh, ll;
        split8(f, hh, ll);
        *(bf16x8*)(&sm[b][0][0] + offh) = hh;
        *(bf16x8*)(&sm[b][0][0] + offl) = ll;
      } else {
        *(bf16x8*)(&sm[b][0][0] + offh) = h;
        *(bf16x8*)(&sm[b][0][0] + offl) = l;
      }
    } else {
      const float* p = A0 + (size_t)(m0 + srow) * K + kg;
      float4 x0 = *(const float4*)(p);
      float4 x1 = *(const float4*)(p + 4);
      f[0] = x0.x; f[1] = x0.y; f[2] = x0.z; f[3] = x0.w;
      f[4] = x1.x; f[5] = x1.y; f[6] = x1.z; f[7] = x1.w;
      if constexpr (AMODE == 1) {
        const float* q = Ax0 + (size_t)(m0 + srow) * K + kg;
        const float* r = Ax1 + (size_t)(m0 + srow) * K + kg;
        float4 y0 = *(const float4*)(q), y1 = *(const float4*)(q + 4);
        float4 z0 = *(const float4*)(r), z1 = *(const float4*)(r + 4);
        f[0] += 0.5f * (y0.x + z0.x); f[1] += 0.5f * (y0.y + z0.y);
        f[2] += 0.5f * (y0.z + z0.z); f[3] += 0.5f * (y0.w + z0.w);
        f[4] += 0.5f * (y1.x + z1.x); f[5] += 0.5f * (y1.y + z1.y);
        f[6] += 0.5f * (y1.z + z1.z); f[7] += 0.5f * (y1.w + z1.w);
      }
      if (scale) {
#pragma unroll
        for (int i = 0; i < 8; ++i) f[i] *= scale[kg + i];
      }
      bf16x8 hh, ll;
      split8(f, hh, ll);
      *(bf16x8*)(&sm[b][0][0] + offh) = hh;
      *(bf16x8*)(&sm[b][0][0] + offl) = ll;
      if constexpr (AMODE == 3) {
        const float* p2 = Ax0 + (size_t)(m0 + srow) * K + kg;
        float4 u0 = *(const float4*)(p2), u1 = *(const float4*)(p2 + 4);
        float g[8] = {u0.x, u0.y, u0.z, u0.w, u1.x, u1.y, u1.z, u1.w};
        bf16x8 gh, gl;
        split8(g, gh, gl);
        *(bf16x8*)(&sm[b][1][0] + offh) = gh;
        *(bf16x8*)(&sm[b][1][0] + offl) = gl;
      }
    }
  };

  f32x4 acc[4][4] = {};
  const int slot = (AMODE == 3) ? (w >> 1) : 0;
  stage(0, 0);
  __syncthreads();
  int steps = Kc / 32;
  for (int s = 0; s < steps; ++s) {
    if (s + 1 < steps) stage((s + 1) & 1, (s + 1) * 32);
    const unsigned char* base = &sm[s & 1][slot][0];
    bf16x8 ah[4], al[4];
#pragma unroll
    for (int i = 0; i < 4; ++i) {
      int row = i * 16 + lr;
      int sz = (row & 7) << 4;
      ah[i] = *(const bf16x8*)(base + ((row * 128 + lk * 2) ^ sz));
      al[i] = *(const bf16x8*)(base + ((row * 128 + 64 + lk * 2) ^ sz));
    }
    int kkg = k0 + s * 32 + lk;
#pragma unroll
    for (int j = 0; j < 4; ++j) {
      int col = n0w + j * 16 + lr;
      size_t bo = (size_t)col * K + kkg;
      bf16x8 bh = *(const bf16x8*)(Bth + bo);
      bf16x8 bl = *(const bf16x8*)(Btl + bo);
#pragma unroll
      for (int i = 0; i < 4; ++i) {
        acc[i][j] = MFMA16(ah[i], bh, acc[i][j], 0, 0, 0);
        acc[i][j] = MFMA16(ah[i], bl, acc[i][j], 0, 0, 0);
        acc[i][j] = MFMA16(al[i], bh, acc[i][j], 0, 0, 0);
      }
    }
    __syncthreads();
  }
  int rr = (lane >> 4) * 4;
#pragma unroll
  for (int i = 0; i < 4; ++i)
#pragma unroll
    for (int j = 0; j < 4; ++j) {
      int col = n0w + j * 16 + lr;
#pragma unroll
      for (int r = 0; r < 4; ++r)
        atomicAdd(&C[(size_t)(m0 + i * 16 + rr + r) * 256 + col], acc[i][j][r]);
    }
}

// ---------------------------------------------------------------------------
// Symmetric dual-Gram + A2 epilogue. grid (32,32), upper-tri blocks 128x128.
//   A2 = 0.125*(w0*relu(Cc@Cc^T) + w1*relu(Cd@Cd^T)) -> split-bf16 (+mirror),
//   rowsums (atomic, incl mirror) and raw diagonal.
// ---------------------------------------------------------------------------
__global__ __launch_bounds__(256, 2) void k_cos2(
    const unsigned short* __restrict__ Ch, const unsigned short* __restrict__ Cl,
    const unsigned short* __restrict__ Dh, const unsigned short* __restrict__ Dl,
    const float* __restrict__ wb, float* __restrict__ rs, float* __restrict__ gP,
    unsigned short* __restrict__ A2h, unsigned short* __restrict__ A2l) {
  int bi = blockIdx.y, bj = blockIdx.x;
  if (bj < bi) return;
  __shared__ unsigned char sm[2][2][16384];  // [buf][A/B][128 rows * 128B]
  const int tid = threadIdx.x;
  const int w = tid >> 6, lane = tid & 63, wm = w >> 1, wn = w & 1;
  const int lr = lane & 15, lk = (lane >> 4) * 8;
  const int rbase = bi * 128, cbase = bj * 128;

  auto stageT = [&](int b, int t01, const unsigned short* Mh, const unsigned short* Ml,
                    int base_row, int kk) {
#pragma unroll
    for (int ss = 0; ss < 2; ++ss) {
      int s = tid + ss * 256;
      int row = s >> 2, kp = (s & 3) * 8;
      size_t go = (size_t)(base_row + row) * 1024 + kk + kp;
      bf16x8 h = *(const bf16x8*)(Mh + go);
      bf16x8 l = *(const bf16x8*)(Ml + go);
      int sz = (row & 7) << 4;
      unsigned char* base = &sm[b][t01][0];
      *(bf16x8*)(base + ((row * 128 + kp * 2) ^ sz)) = h;
      *(bf16x8*)(base + ((row * 128 + 64 + kp * 2) ^ sz)) = l;
    }
  };
  auto gram = [&](const unsigned short* Mh, const unsigned short* Ml, f32x4 (&acc)[4][4]) {
    stageT(0, 0, Mh, Ml, rbase, 0);
    stageT(0, 1, Mh, Ml, cbase, 0);
    __syncthreads();
    for (int s = 0; s < 32; ++s) {
      if (s + 1 < 32) {
        stageT((s + 1) & 1, 0, Mh, Ml, rbase, (s + 1) * 32);
        stageT((s + 1) & 1, 1, Mh, Ml, cbase, (s + 1) * 32);
      }
      const unsigned char* ba = &sm[s & 1][0][0];
      const unsigned char* bb = &sm[s & 1][1][0];
      bf16x8 ah[4], al[4];
#pragma unroll
      for (int i = 0; i < 4; ++i) {
        int row = wm * 64 + i * 16 + lr;
        int sz = (row & 7) << 4;
        ah[i] = *(const bf16x8*)(ba + ((row * 128 + lk * 2) ^ sz));
        al[i] = *(const bf16x8*)(ba + ((row * 128 + 64 + lk * 2) ^ sz));
      }
#pragma unroll
      for (int j = 0; j < 4; ++j) {
        int rowb = wn * 64 + j * 16 + lr;
        int sz = (rowb & 7) << 4;
        bf16x8 bh = *(const bf16x8*)(bb + ((rowb * 128 + lk * 2) ^ sz));
        bf16x8 bl = *(const bf16x8*)(bb + ((rowb * 128 + 64 + lk * 2) ^ sz));
#pragma unroll
        for (int i = 0; i < 4; ++i) {
          acc[i][j] = MFMA16(ah[i], bh, acc[i][j], 0, 0, 0);
          acc[i][j] = MFMA16(ah[i], bl, acc[i][j], 0, 0, 0);
          acc[i][j] = MFMA16(al[i], bh, acc[i][j], 0, 0, 0);
        }
      }
      __syncthreads();
    }
  };

  f32x4 aC[4][4] = {}, aD[4][4] = {};
  gram(Ch, Cl, aC);
  gram(Dh, Dl, aD);

  float w0 = wb[0] * 0.125f, w1 = wb[1] * 0.125f;
  int rr = (lane >> 4) * 4;
  bool diag = (bi == bj);
#pragma unroll
  for (int i = 0; i < 4; ++i) {
#pragma unroll
    for (int r = 0; r < 4; ++r) {
      int row = rbase + wm * 64 + i * 16 + rr + r;
      float p = 0.f;
#pragma unroll
      for (int j = 0; j < 4; ++j) {
        int col = cbase + wn * 64 + j * 16 + lr;
        float v = w0 * fmaxf(aC[i][j][r], 0.f) + w1 * fmaxf(aD[i][j][r], 0.f);
        p += v;
        unsigned short h, l;
        split1(v, h, l);
        size_t o = (size_t)row * 4096 + col;
        A2h[o] = h; A2l[o] = l;
        if (diag && row == col) gP[row] = v;
      }
      p += __shfl_xor(p, 1); p += __shfl_xor(p, 2);
      p += __shfl_xor(p, 4); p += __shfl_xor(p, 8);
      if (lr == 0) atomicAdd(&rs[row], p);
    }
  }
  if (!diag) {
#pragma unroll
    for (int j = 0; j < 4; ++j) {
      int col = cbase + wn * 64 + j * 16 + lr;
      float cs = 0.f;
#pragma unroll
      for (int i = 0; i < 4; ++i) {
        int row0 = rbase + wm * 64 + i * 16 + rr;
        ushort4 hv, lv;
#pragma unroll
        for (int r = 0; r < 4; ++r) {
          float v = w0 * fmaxf(aC[i][j][r], 0.f) + w1 * fmaxf(aD[i][j][r], 0.f);
          cs += v;
          unsigned short h, l;
          split1(v, h, l);
          ((unsigned short*)&hv)[r] = h;
          ((unsigned short*)&lv)[r] = l;
        }
        *(ushort4*)(A2h + (size_t)col * 4096 + row0) = hv;
        *(ushort4*)(A2l + (size_t)col * 4096 + row0) = lv;
      }
      cs += __shfl_xor(cs, 16); cs += __shfl_xor(cs, 32);
      if (lane < 16) atomicAdd(&rs[col], cs);
    }
  }
}

// ---------------------------------------------------------------------------
// Epilogues
// ---------------------------------------------------------------------------
// PRENORM=0: out = relu(dn*acc + dn*dfix*xw + b); PRENORM=1 (A pre-normalized):
//            out = relu(acc + dn*dfix*xw + b);   dfix = (1-diag)*dn
template <int PRENORM>
__global__ __launch_bounds__(256) void k_ep_prop(
    const float* __restrict__ acc, const float* __restrict__ xw,
    const float* __restrict__ dvec, const float* __restrict__ diag,
    const float* __restrict__ bias, float* __restrict__ out) {
  int idx = blockIdx.x * 256 + threadIdx.x;
  int i = idx * 4, row = i >> 8, c = i & 255;
  float4 a = *(const float4*)(acc + i);
  float4 x = *(const float4*)(xw + i);
  float4 b = *(const float4*)(bias + c);
  float dn = dvec[row], dfix = (1.f - diag[row]) * dn * dn;
  float s = PRENORM ? 1.f : dn;
  float4 o;
  o.x = fmaxf(s * a.x + dfix * x.x + b.x, 0.f);
  o.y = fmaxf(s * a.y + dfix * x.y + b.y, 0.f);
  o.z = fmaxf(s * a.z + dfix * x.z + b.z, 0.f);
  o.w = fmaxf(s * a.w + dfix * x.w + b.w, 0.f);
  *(float4*)(out + i) = o;
}

__global__ __launch_bounds__(256) void k_ep_heads(
    const float* __restrict__ acc, const float* __restrict__ b0,
    const float* __restrict__ b1, const float* __restrict__ b2,
    const float* __restrict__ b3, float* __restrict__ o0, float* __restrict__ o1,
    float* __restrict__ o2, float* __restrict__ o3) {
  int idx = blockIdx.x * 256 + threadIdx.x;
  int i = idx * 4, row = i >> 8, c = i & 255;
  int head = c >> 6, cc = c & 63;
  const float* bias = (head == 0) ? b0 : (head == 1) ? b1 : (head == 2) ? b2 : b3;
  float* outp = (head == 0) ? o0 : (head == 1) ? o1 : (head == 2) ? o2 : o3;
  float4 a = *(const float4*)(acc + i);
  float4 b = *(const float4*)(bias + cc);
  float4 o;
  o.x = fmaxf(a.x + b.x, 0.f); o.y = fmaxf(a.y + b.y, 0.f);
  o.z = fmaxf(a.z + b.z, 0.f); o.w = fmaxf(a.w + b.w, 0.f);
  if (head & 1) {
    o.x = 1.f / (1.f + expf(-o.x)); o.y = 1.f / (1.f + expf(-o.y));
    o.z = 1.f / (1.f + expf(-o.z)); o.w = 1.f / (1.f + expf(-o.w));
  }
  *(float4*)(outp + (size_t)row * 64 + cc) = o;
}

// ---------------------------------------------------------------------------
// Attention
// ---------------------------------------------------------------------------
__global__ __launch_bounds__(256) void k_att(
    const float* __restrict__ z0, const float* __restrict__ z1,
    const float* __restrict__ z2, const float* __restrict__ z3,
    const float* __restrict__ W1, const float* __restrict__ b1,
    const float* __restrict__ w2, float* __restrict__ s_out) {
  int k = blockIdx.y;
  const float* z = (k == 0) ? z0 : (k == 1) ? z1 : (k == 2) ? z2 : z3;
  int wave = threadIdx.x >> 6, lane = threadIdx.x & 63;
  float total = 0.f;
  for (int n = blockIdx.x * 4 + wave; n < 4096; n += gridDim.x * 4) {
    float s0 = 0.f, s1 = 0.f;
    const float* zr = z + (size_t)n * 256;
    for (int h = 0; h < 256; ++h) {
      float zv = zr[h];
      s0 += zv * W1[h * 128 + lane];
      s1 += zv * W1[h * 128 + 64 + lane];
    }
    float v = tanhf(s0 + b1[lane]) * w2[lane] + tanhf(s1 + b1[64 + lane]) * w2[64 + lane];
    v = wave_reduce_sum(v);
    if (lane == 0) total += v;
  }
  if (lane == 0) atomicAdd(&s_out[k], total);
}

__global__ void k_beta(const float* __restrict__ s, float* __restrict__ bb) {
  if (threadIdx.x == 0 && blockIdx.x == 0) {
    const float inv = 1.f / 4096.f;
    float c0 = s[0] * inv, c1 = s[1] * inv;
    float m = fmaxf(c0, c1);
    float e0 = expf(c0 - m), e1 = expf(c1 - m);
    float is = 1.f / (e0 + e1);
    bb[0] = e0 * is; bb[1] = e1 * is;
    float d0 = s[2] * inv, d1 = s[3] * inv, d2 = s[4] * inv, d3 = s[5] * inv;
    float md = fmaxf(fmaxf(d0, d1), fmaxf(d2, d3));
    float f0 = expf(d0 - md), f1 = expf(d1 - md), f2 = expf(d2 - md), f3 = expf(d3 - md);
    float id = 1.f / (f0 + f1 + f2 + f3);
    bb[2] = f0 * id; bb[3] = f1 * id; bb[4] = f2 * id; bb[5] = f3 * id;
  }
}

__global__ __launch_bounds__(256) void k_agg(
    const float* __restrict__ cr0, const float* __restrict__ cr1,
    const float* __restrict__ dr0, const float* __restrict__ dr1,
    const float* __restrict__ bb, float* __restrict__ cagg, float* __restrict__ dagg) {
  size_t i = ((size_t)blockIdx.x * 256 + threadIdx.x) * 4;
  float4 a = *(const float4*)(cr0 + i);
  float4 b = *(const float4*)(cr1 + i);
  float4 c = *(const float4*)(dr0 + i);
  float4 d = *(const float4*)(dr1 + i);
  float bc0 = bb[0], bc1 = bb[1], bd0 = bb[2], bd1 = bb[3], bd2 = bb[4], bd3 = bb[5];
  float4 ca, da;
  ca.x = bc0 * a.x + bc1 * b.x; ca.y = bc0 * a.y + bc1 * b.y;
  ca.z = bc0 * a.z + bc1 * b.z; ca.w = bc0 * a.w + bc1 * b.w;
  da.x = bd0 * a.x + bd1 * b.x + bd2 * c.x + bd3 * d.x;
  da.y = bd0 * a.y + bd1 * b.y + bd2 * c.y + bd3 * d.y;
  da.z = bd0 * a.z + bd1 * b.z + bd2 * c.z + bd3 * d.z;
  da.w = bd0 * a.w + bd1 * b.w + bd2 * c.w + bd3 * d.w;
  *(float4*)(cagg + i) = ca;
  *(float4*)(dagg + i) = da;
}

__global__ __launch_bounds__(256) void k_cn(const float* __restrict__ mu,
                                            const float* __restrict__ Wt,
                                            unsigned short* __restrict__ Chh,
                                            unsigned short* __restrict__ Cll) {
  int g = blockIdx.x * 4 + (threadIdx.x >> 6);
  int lane = threadIdx.x & 63;
  int n = g >> 4, p = g & 15;
  float v = mu[(size_t)n * 64 + lane] * Wt[p * 64 + lane];
  float ss = v * v;
#pragma unroll
  for (int off = 32; off > 0; off >>= 1) ss += __shfl_xor(ss, off);
  float nrm = fmaxf(sqrtf(ss), 1e-12f);
  float r = v / nrm;
  unsigned short h, l;
  split1(r, h, l);
  size_t o = (size_t)n * 1024 + p * 64 + lane;
  Chh[o] = h; Cll[o] = l;
}

__global__ __launch_bounds__(256) void k_gather(
    const int* __restrict__ xs, const float* __restrict__ U1, const float* __restrict__ U2,
    const float* __restrict__ V1, const float* __restrict__ V2, float* __restrict__ out) {
  int b = blockIdx.x, j = threadIdx.x;
  int row = xs[b];
  size_t r = (size_t)row * 256;
  out[(size_t)b * 512 + j] = 0.5f * (U1[r + j] + U2[r + j]);
  out[(size_t)b * 512 + 256 + j] = 0.5f * (V1[r + j] + V2[r + j]);
}

// ---------------------------------------------------------------------------
extern "C" void kernel_launch(void* const* d_in, const int* in_sizes, int n_in,
                              void* d_out, int out_size, void* d_ws, size_t ws_size,
                              hipStream_t stream) {
  const float* c0adj = (const float*)d_in[0];
  const float* c1adj = (const float*)d_in[1];
  const float* d0adj = (const float*)d_in[2];
  const float* d1adj = (const float*)d_in[3];
  const float* feats = (const float*)d_in[4];
  const float* W_comm = (const float*)d_in[5];
  const float* b_comm = (const float*)d_in[6];
  const float* W_diff = (const float*)d_in[7];
  const float* b_diff = (const float*)d_in[8];
  const float* W_catt1 = (const float*)d_in[9];
  const float* b_catt1 = (const float*)d_in[10];
  const float* w_catt2 = (const float*)d_in[11];
  const float* W_datt1 = (const float*)d_in[12];
  const float* b_datt1 = (const float*)d_in[13];
  const float* w_datt2 = (const float*)d_in[14];
  const float* W_mu_c = (const float*)d_in[15];
  const float* b_mu_c = (const float*)d_in[16];
  const float* W_var_c = (const float*)d_in[17];
  const float* b_var_c = (const float*)d_in[18];
  const float* W_mu_d = (const float*)d_in[19];
  const float* b_mu_d = (const float*)d_in[20];
  const float* W_var_d = (const float*)d_in[21];
  const float* b_var_d = (const float*)d_in[22];
  const float* W_z1_1 = (const float*)d_in[23];
  const float* b_z1_1 = (const float*)d_in[24];
  const float* W_z1_2 = (const float*)d_in[25];
  const float* b_z1_2 = (const float*)d_in[26];
  const float* wb_z1 = (const float*)d_in[27];
  const float* Wt_c = (const float*)d_in[28];
  const float* Wt_d = (const float*)d_in[29];
  const float* W_z2_1 = (const float*)d_in[30];
  const float* b_z2_1 = (const float*)d_in[31];
  const float* W_z2_2 = (const float*)d_in[32];
  const float* b_z2_2 = (const float*)d_in[33];
  const float* wb_z2 = (const float*)d_in[34];
  const int* xs = (const int*)d_in[35];

  float* out = (float*)d_out;
  float* out_muc = out + 65536;
  float* out_varc = out + 327680;
  float* out_mud = out + 589824;
  float* out_vard = out + 851968;

  float* ws = (float*)d_ws;
  const size_t M1 = 1048576;  // 4 MB of floats
  float* xw_comm = ws + 0 * M1;
  float* xw_diff = ws + 1 * M1;
  float* xw_z1 = ws + 2 * M1;
  float* xw_z2 = ws + 3 * M1;
  float* cr0 = ws + 4 * M1;
  float* cr1 = ws + 5 * M1;
  float* dr0 = ws + 6 * M1;
  float* dr1 = ws + 7 * M1;
  float* u1 = ws + 8 * M1;
  float* u2 = ws + 9 * M1;
  float* v1 = ws + 10 * M1;
  float* v2 = ws + 11 * M1;
  float* uw = ws + 12 * M1;
  float* cagg = ws + 13 * M1;
  float* dagg = ws + 14 * M1;
  float* accb = ws + 15 * M1;
  unsigned short* Bth = (unsigned short*)(ws + 16 * M1);
  unsigned short* Btl = Bth + (size_t)256 * 4096;
  unsigned short* Cch = (unsigned short*)(ws + 17 * M1);
  unsigned short* Ccl = (unsigned short*)(ws + 19 * M1);
  unsigned short* Cdh = (unsigned short*)(ws + 21 * M1);
  unsigned short* Cdl = (unsigned short*)(ws + 23 * M1);
  unsigned short* A1h = (unsigned short*)(ws + 25 * M1);
  unsigned short* A1l = (unsigned short*)(ws + 33 * M1);
  float* tmpb = ws + 41 * M1;                             // 16 M1 fp32
  unsigned short* A2h = (unsigned short*)(ws + 41 * M1);  // overlays tmpb
  unsigned short* A2l = (unsigned short*)(ws + 49 * M1);
  float* vecs = ws + 57 * M1;
#define VV(i) (vecs + (size_t)(i) * 4096)
  float* rs_c0 = VV(0); float* rs_c1 = VV(1); float* rs_d0 = VV(2); float* rs_d1 = VV(3);
  float* dg_c0 = VV(4); float* dg_c1 = VV(5); float* dg_d0 = VV(6); float* dg_d1 = VV(7);
  float* cs_tmp = VV(8); float* rs_A2 = VV(9);
  float* d_c0 = VV(10); float* d_c1 = VV(11); float* d_dd0 = VV(12); float* d_dd1 = VV(13);
  float* d_A1 = VV(14); float* d_A2 = VV(15);
  float* gP_dd0 = VV(16); float* gP_dd1 = VV(17); float* gP_A1 = VV(18); float* gP_A2 = VV(19);
  float* satt = VV(20);
  float* beta = satt + 8;

  hipMemsetAsync(cs_tmp, 0, 2 * 4096 * sizeof(float), stream);  // cs_tmp + rs_A2
  hipMemsetAsync(satt, 0, 64, stream);
  hipMemsetAsync(xw_comm, 0, 4 * M1 * sizeof(float), stream);

  // adjacency pass
  k_rowsums<<<256, 256, 0, stream>>>(c0adj, c1adj, d0adj, d1adj, wb_z1, tmpb,
                                     rs_c0, rs_c1, rs_d0, rs_d1, dg_c0, dg_c1, dg_d0, dg_d1);
  k_colsum<<<dim3(16, 32), 256, 0, stream>>>(tmpb, cs_tmp);
  k_fin<<<16, 256, 0, stream>>>(rs_c0, rs_c1, rs_d0, rs_d1, dg_c0, dg_c1, dg_d0, dg_d1,
                                cs_tmp, wb_z1, d_c0, d_c1, d_dd0, d_dd1, d_A1,
                                gP_dd0, gP_dd1, gP_A1);
  k_addTn<<<dim3(64, 64), 256, 0, stream>>>(tmpb, d_A1, A1h, A1l);

  // feats @ W (4x): K=512, Kc=128
  const float* Wf[4] = {W_comm, W_diff, W_z1_1, W_z2_1};
  float* xwf[4] = {xw_comm, xw_diff, xw_z1, xw_z2};
  for (int t = 0; t < 4; ++t) {
    k_prepB<<<dim3(8, 4), 256, 0, stream>>>(Wf[t], Bth, Btl, 512, 256);
    k_gemm<0><<<dim3(4, 64), 256, 0, stream>>>(feats, nullptr, nullptr, nullptr, nullptr,
                                               nullptr, Bth, Btl, xwf[t], 512, 128);
  }

  // comm props: B = xw_comm (prepped once), A-scale = dvec
  k_prepB<<<dim3(64, 4), 256, 0, stream>>>(xw_comm, Bth, Btl, 4096, 256);
  hipMemsetAsync(accb, 0, M1 * sizeof(float), stream);
  k_gemm<0><<<dim3(8, 64), 256, 0, stream>>>(c0adj, nullptr, nullptr, nullptr, nullptr,
                                             d_c0, Bth, Btl, accb, 4096, 512);
  k_ep_prop<0><<<1024, 256, 0, stream>>>(accb, xw_comm, d_c0, dg_c0, b_comm, cr0);
  hipMemsetAsync(accb, 0, M1 * sizeof(float), stream);
  k_gemm<0><<<dim3(8, 64), 256, 0, stream>>>(c1adj, nullptr, nullptr, nullptr, nullptr,
                                             d_c1, Bth, Btl, accb, 4096, 512);
  k_ep_prop<0><<<1024, 256, 0, stream>>>(accb, xw_comm, d_c1, dg_c1, b_comm, cr1);

  // diff props
  k_prepB<<<dim3(64, 4), 256, 0, stream>>>(xw_diff, Bth, Btl, 4096, 256);
  hipMemsetAsync(accb, 0, M1 * sizeof(float), stream);
  k_gemm<1><<<dim3(8, 64), 256, 0, stream>>>(d0adj, c0adj, c1adj, nullptr, nullptr,
                                             d_dd0, Bth, Btl, accb, 4096, 512);
  k_ep_prop<0><<<1024, 256, 0, stream>>>(accb, xw_diff, d_dd0, gP_dd0, b_diff, dr0);
  hipMemsetAsync(accb, 0, M1 * sizeof(float), stream);
  k_gemm<1><<<dim3(8, 64), 256, 0, stream>>>(d1adj, c0adj, c1adj, nullptr, nullptr,
                                             d_dd1, Bth, Btl, accb, 4096, 512);
  k_ep_prop<0><<<1024, 256, 0, stream>>>(accb, xw_diff, d_dd1, gP_dd1, b_diff, dr1);

  // z1: U1 (A1 pre-normalized)
  k_prepB<<<dim3(64, 4), 256, 0, stream>>>(xw_z1, Bth, Btl, 4096, 256);
  hipMemsetAsync(accb, 0, M1 * sizeof(float), stream);
  k_gemm<2><<<dim3(8, 64), 256, 0, stream>>>(nullptr, nullptr, nullptr, A1h, A1l,
                                             nullptr, Bth, Btl, accb, 4096, 512);
  k_ep_prop<1><<<1024, 256, 0, stream>>>(accb, xw_z1, d_A1, gP_A1, b_z1_1, u1);
  // uw = U1 @ W_z1_2
  k_prepB<<<dim3(4, 4), 256, 0, stream>>>(W_z1_2, Bth, Btl, 256, 256);
  hipMemsetAsync(uw, 0, M1 * sizeof(float), stream);
  k_gemm<0><<<dim3(4, 64), 256, 0, stream>>>(u1, nullptr, nullptr, nullptr, nullptr,
                                             nullptr, Bth, Btl, uw, 256, 64);
  // U2
  k_prepB<<<dim3(64, 4), 256, 0, stream>>>(uw, Bth, Btl, 4096, 256);
  hipMemsetAsync(accb, 0, M1 * sizeof(float), stream);
  k_gemm<2><<<dim3(8, 64), 256, 0, stream>>>(nullptr, nullptr, nullptr, A1h, A1l,
                                             nullptr, Bth, Btl, accb, 4096, 512);
  k_ep_prop<1><<<1024, 256, 0, stream>>>(accb, uw, d_A1, gP_A1, b_z1_2, u2);

  // attention
  k_att<<<dim3(128, 2), 256, 0, stream>>>(cr0, cr1, cr0, cr0, W_catt1, b_catt1, w_catt2, satt);
  k_att<<<dim3(128, 4), 256, 0, stream>>>(cr0, cr1, dr0, dr1, W_datt1, b_datt1, w_datt2, satt + 2);
  k_beta<<<1, 64, 0, stream>>>(satt, beta);
  k_agg<<<1024, 256, 0, stream>>>(cr0, cr1, dr0, dr1, beta, cagg, dagg);

  // heads: one dual-A GEMM, 4 heads as 4 col-blocks
  k_prepB<<<dim3(4, 1), 256, 0, stream>>>(W_mu_c, Bth + 0 * 64 * 256, Btl + 0 * 64 * 256, 256, 64);
  k_prepB<<<dim3(4, 1), 256, 0, stream>>>(W_var_c, Bth + 1 * 64 * 256, Btl + 1 * 64 * 256, 256, 64);
  k_prepB<<<dim3(4, 1), 256, 0, stream>>>(W_mu_d, Bth + 2 * 64 * 256, Btl + 2 * 64 * 256, 256, 64);
  k_prepB<<<dim3(4, 1), 256, 0, stream>>>(W_var_d, Bth + 3 * 64 * 256, Btl + 3 * 64 * 256, 256, 64);
  hipMemsetAsync(accb, 0, M1 * sizeof(float), stream);
  k_gemm<3><<<dim3(4, 64), 256, 0, stream>>>(cagg, dagg, nullptr, nullptr, nullptr,
                                             nullptr, Bth, Btl, accb, 256, 64);
  k_ep_heads<<<1024, 256, 0, stream>>>(accb, b_mu_c, b_var_c, b_mu_d, b_var_d,
                                       out_muc, out_varc, out_mud, out_vard);

  // cosine contexts
  k_cn<<<16384, 256, 0, stream>>>(out_muc, Wt_c, Cch, Ccl);
  k_cn<<<16384, 256, 0, stream>>>(out_mud, Wt_d, Cdh, Cdl);

  // A2 (symmetric dual-Gram) + degrees
  k_cos2<<<dim3(32, 32), 256, 0, stream>>>(Cch, Ccl, Cdh, Cdl, wb_z2, rs_A2, gP_A2, A2h, A2l);
  k_dA2<<<16, 256, 0, stream>>>(rs_A2, gP_A2, d_A2);

  // z2: V1 (A2 raw pair, scale at staging)
  k_prepB<<<dim3(64, 4), 256, 0, stream>>>(xw_z2, Bth, Btl, 4096, 256);
  hipMemsetAsync(accb, 0, M1 * sizeof(float), stream);
  k_gemm<2><<<dim3(8, 64), 256, 0, stream>>>(nullptr, nullptr, nullptr, A2h, A2l,
                                             d_A2, Bth, Btl, accb, 4096, 512);
  k_ep_prop<0><<<1024, 256, 0, stream>>>(accb, xw_z2, d_A2, gP_A2, b_z2_1, v1);
  // vw = V1 @ W_z2_2
  k_prepB<<<dim3(4, 4), 256, 0, stream>>>(W_z2_2, Bth, Btl, 256, 256);
  hipMemsetAsync(uw, 0, M1 * sizeof(float), stream);
  k_gemm<0><<<dim3(4, 64), 256, 0, stream>>>(v1, nullptr, nullptr, nullptr, nullptr,
                                             nullptr, Bth, Btl, uw, 256, 64);
  // V2
  k_prepB<<<dim3(64, 4), 256, 0, stream>>>(uw, Bth, Btl, 4096, 256);
  hipMemsetAsync(accb, 0, M1 * sizeof(float), stream);
  k_gemm<2><<<dim3(8, 64), 256, 0, stream>>>(nullptr, nullptr, nullptr, A2h, A2l,
                                             d_A2, Bth, Btl, accb, 4096, 512);
  k_ep_prop<0><<<1024, 256, 0, stream>>>(accb, uw, d_A2, gP_A2, b_z2_2, v2);

  // h[xs]
  k_gather<<<128, 256, 0, stream>>>(xs, u1, u2, v1, v2, out);
}